// Round 1
// baseline (3768.420 us; speedup 1.0000x reference)
//
#include <hip/hip_runtime.h>

#define N_NODES 50000
#define N_EDGES 300000
#define IN_CH 256
#define HID 512

// ---------- index dtype detection (int32 vs int64, decided on-device) ----------
// If edge_index is int64 little-endian with values < 2^31, every odd 32-bit word
// (the high word) of the first 600000 words is zero. If int32, odd words are
// random indices in [0, 50000) -> essentially impossible to be all zero.
__global__ void detect_idx64(const unsigned int* __restrict__ ei, int* __restrict__ flag) {
    __shared__ int anynz;
    if (threadIdx.x == 0) anynz = 0;
    __syncthreads();
    int local = 0;
    for (int i = 1 + 2 * (int)threadIdx.x; i < 2 * N_EDGES; i += 2 * (int)blockDim.x)
        local |= (ei[i] != 0u);
    if (local) atomicOr(&anynz, 1);
    __syncthreads();
    if (threadIdx.x == 0) *flag = anynz ? 0 : 1;   // 1 => int64
}

__device__ __forceinline__ int load_idx(const void* ei, int i, int is64) {
    if (is64) return (int)((const long long*)ei)[i];
    return ((const int*)ei)[i];
}

// ---------- degree / normalization ----------
__global__ void deg_init(float* __restrict__ deg) {
    int i = blockIdx.x * blockDim.x + threadIdx.x;
    if (i < N_NODES) deg[i] = 1.0f;   // self-loop weight
}

__global__ void deg_accum(const void* __restrict__ ei, const float* __restrict__ ew,
                          float* __restrict__ deg, const int* __restrict__ flag) {
    int e = blockIdx.x * blockDim.x + threadIdx.x;
    if (e >= N_EDGES) return;
    int is64 = *flag;
    int d = load_idx(ei, N_EDGES + e, is64);
    atomicAdd(&deg[d], ew[e]);
}

__global__ void dis_kernel(const float* __restrict__ deg, float* __restrict__ dis) {
    int i = blockIdx.x * blockDim.x + threadIdx.x;
    if (i < N_NODES) {
        float dg = deg[i];
        dis[i] = (dg > 0.f) ? (1.0f / sqrtf(dg)) : 0.f;
    }
}

// ---------- aggregation: init with self-loop contribution ----------
template <int C>
__global__ void init_agg(const float* __restrict__ x, const float* __restrict__ dis,
                         float* __restrict__ agg) {
    int i = blockIdx.x;           // node
    float s = dis[i];
    s = s * s;                    // self-loop norm = dis[i]*1*dis[i]
    const float4* xr = (const float4*)(x + (size_t)i * C);
    float4* ar = (float4*)(agg + (size_t)i * C);
    for (int c = threadIdx.x; c < C / 4; c += blockDim.x) {
        float4 v = xr[c];
        ar[c] = make_float4(v.x * s, v.y * s, v.z * s, v.w * s);
    }
}

// ---------- scatter-add edges: one wave (64 lanes) per edge ----------
template <int C>
__global__ void scatter_edges(const void* __restrict__ ei, const float* __restrict__ ew,
                              const float* __restrict__ dis, const float* __restrict__ x,
                              float* __restrict__ agg, const int* __restrict__ flag) {
    int e = blockIdx.x * (blockDim.x / 64) + (threadIdx.x >> 6);
    if (e >= N_EDGES) return;
    int lane = threadIdx.x & 63;
    int is64 = *flag;
    int s = load_idx(ei, e, is64);
    int d = load_idx(ei, N_EDGES + e, is64);
    float coef = dis[s] * ew[e] * dis[d];
    const float4* xs = (const float4*)(x + (size_t)s * C);
    float* ad = agg + (size_t)d * C;
#pragma unroll
    for (int c0 = lane; c0 < C / 4; c0 += 64) {
        float4 v = xs[c0];
        atomicAdd(&ad[c0 * 4 + 0], coef * v.x);
        atomicAdd(&ad[c0 * 4 + 1], coef * v.y);
        atomicAdd(&ad[c0 * 4 + 2], coef * v.z);
        atomicAdd(&ad[c0 * 4 + 3], coef * v.w);
    }
}

// ---------- f32 GEMM: out[n,512] = X[n,K] @ W[512,K]^T + bias (optional PReLU) ----------
template <int K, bool PRELU>
__global__ __launch_bounds__(256) void gemm_kernel(
    const float* __restrict__ X, const float* __restrict__ Wt,
    const float* __restrict__ bias, const float* __restrict__ prelu_a,
    float* __restrict__ out, int n)
{
    __shared__ float As[32][68];   // [k][row], padded for bank spread, 16B-aligned rows
    __shared__ float Bs[32][68];   // [k][col]
    const int tid = threadIdx.x;
    const int tx = tid & 15;       // output col group
    const int ty = tid >> 4;       // output row group
    const int row0 = blockIdx.x * 64;
    const int col0 = blockIdx.y * 64;
    float acc[4][4] = {};

    for (int k0 = 0; k0 < K; k0 += 32) {
        __syncthreads();
        // stage 64x32 of X and W into LDS (transposed to [k][m]) via float4 loads
        for (int l = tid; l < 512; l += 256) {
            int r = l >> 3;          // 0..63
            int c4 = l & 7;          // float4 index along k
            float4 va;
            if (row0 + r < n)
                va = *(const float4*)(X + (size_t)(row0 + r) * K + k0 + c4 * 4);
            else
                va = make_float4(0.f, 0.f, 0.f, 0.f);
            As[c4 * 4 + 0][r] = va.x; As[c4 * 4 + 1][r] = va.y;
            As[c4 * 4 + 2][r] = va.z; As[c4 * 4 + 3][r] = va.w;
            float4 vb = *(const float4*)(Wt + (size_t)(col0 + r) * K + k0 + c4 * 4);
            Bs[c4 * 4 + 0][r] = vb.x; Bs[c4 * 4 + 1][r] = vb.y;
            Bs[c4 * 4 + 2][r] = vb.z; Bs[c4 * 4 + 3][r] = vb.w;
        }
        __syncthreads();
#pragma unroll
        for (int kk = 0; kk < 32; ++kk) {
            const float4 av = *(const float4*)&As[kk][ty * 4];
            const float4 bv = *(const float4*)&Bs[kk][tx * 4];
            const float a[4] = {av.x, av.y, av.z, av.w};
            const float b[4] = {bv.x, bv.y, bv.z, bv.w};
#pragma unroll
            for (int i = 0; i < 4; ++i)
#pragma unroll
                for (int j = 0; j < 4; ++j)
                    acc[i][j] += a[i] * b[j];
        }
    }

    // epilogue
    const float ap = PRELU ? *prelu_a : 0.f;
    const float4 bv = *(const float4*)&bias[col0 + tx * 4];
    const float bb[4] = {bv.x, bv.y, bv.z, bv.w};
#pragma unroll
    for (int i = 0; i < 4; ++i) {
        int gr = row0 + ty * 4 + i;
        if (gr < n) {
            float4 o;
            float v0 = acc[i][0] + bb[0];
            float v1 = acc[i][1] + bb[1];
            float v2 = acc[i][2] + bb[2];
            float v3 = acc[i][3] + bb[3];
            if (PRELU) {
                v0 = (v0 >= 0.f) ? v0 : ap * v0;
                v1 = (v1 >= 0.f) ? v1 : ap * v1;
                v2 = (v2 >= 0.f) ? v2 : ap * v2;
                v3 = (v3 >= 0.f) ? v3 : ap * v3;
            }
            o.x = v0; o.y = v1; o.z = v2; o.w = v3;
            *(float4*)(out + (size_t)gr * HID + col0 + tx * 4) = o;
        }
    }
}

extern "C" void kernel_launch(void* const* d_in, const int* in_sizes, int n_in,
                              void* d_out, int out_size, void* d_ws, size_t ws_size,
                              hipStream_t stream) {
    const float* x  = (const float*)d_in[0];
    const void*  ei = d_in[1];
    const float* ew = (const float*)d_in[2];
    const float* W1 = (const float*)d_in[3];
    const float* b1 = (const float*)d_in[4];
    const float* W2 = (const float*)d_in[5];
    const float* b2 = (const float*)d_in[6];
    const float* pa = (const float*)d_in[7];
    float* out = (float*)d_out;

    float* ws   = (float*)d_ws;
    float* agg  = ws;                                  // reused: 12.8M floats (L1), 25.6M floats (L2)
    float* deg  = ws + (size_t)N_NODES * HID;          // 25.6M offset
    float* dis  = deg + N_NODES;
    int*   flag = (int*)(dis + N_NODES);

    const int NB = (N_NODES + 255) / 256;
    const int EB = (N_EDGES + 255) / 256;

    detect_idx64<<<1, 256, 0, stream>>>((const unsigned int*)ei, flag);
    deg_init<<<NB, 256, 0, stream>>>(deg);
    deg_accum<<<EB, 256, 0, stream>>>(ei, ew, deg, flag);
    dis_kernel<<<NB, 256, 0, stream>>>(deg, dis);

    // ----- layer 1: aggregate x (256 ch) then GEMM(W1)+bias+PReLU -> d_out (=p) -----
    init_agg<IN_CH><<<N_NODES, 64, 0, stream>>>(x, dis, agg);
    scatter_edges<IN_CH><<<N_EDGES / 4, 256, 0, stream>>>(ei, ew, dis, x, agg, flag);
    gemm_kernel<IN_CH, true><<<dim3((N_NODES + 63) / 64, HID / 64), 256, 0, stream>>>(
        agg, W1, b1, pa, out, N_NODES);

    // ----- layer 2: aggregate p (512 ch) then GEMM(W2)+bias -> d_out -----
    init_agg<HID><<<N_NODES, 128, 0, stream>>>(out, dis, agg);
    scatter_edges<HID><<<N_EDGES / 4, 256, 0, stream>>>(ei, ew, dis, out, agg, flag);
    gemm_kernel<HID, false><<<dim3((N_NODES + 63) / 64, HID / 64), 256, 0, stream>>>(
        agg, W2, b2, pa, out, N_NODES);
}

// Round 2
// 1046.890 us; speedup vs baseline: 3.5996x; 3.5996x over previous
//
#include <hip/hip_runtime.h>

#define N_NODES 50000
#define N_EDGES 300000
#define IN_CH 256
#define HID 512

// ---------- index dtype detection (int32 vs int64, decided on-device) ----------
__global__ void detect_idx64(const unsigned int* __restrict__ ei, int* __restrict__ flag) {
    __shared__ int anynz;
    if (threadIdx.x == 0) anynz = 0;
    __syncthreads();
    int local = 0;
    for (int i = 1 + 2 * (int)threadIdx.x; i < 2 * N_EDGES; i += 2 * (int)blockDim.x)
        local |= (ei[i] != 0u);
    if (local) atomicOr(&anynz, 1);
    __syncthreads();
    if (threadIdx.x == 0) *flag = anynz ? 0 : 1;   // 1 => int64
}

__device__ __forceinline__ int load_idx(const void* ei, int i, int is64) {
    if (is64) return (int)((const long long*)ei)[i];
    return ((const int*)ei)[i];
}

// ---------- init: deg=1 (self-loop), counts=0, cursor=0 ----------
__global__ void init_arrays(float* __restrict__ deg, int* __restrict__ counts,
                            int* __restrict__ cursor) {
    int i = blockIdx.x * blockDim.x + threadIdx.x;
    if (i < N_NODES) { deg[i] = 1.0f; counts[i] = 0; cursor[i] = 0; }
}

// ---------- per-edge: weighted degree + dst histogram ----------
__global__ void deg_hist(const void* __restrict__ ei, const float* __restrict__ ew,
                         float* __restrict__ deg, int* __restrict__ counts,
                         const int* __restrict__ flag) {
    int e = blockIdx.x * blockDim.x + threadIdx.x;
    if (e >= N_EDGES) return;
    int is64 = *flag;
    int d = load_idx(ei, N_EDGES + e, is64);
    atomicAdd(&deg[d], ew[e]);
    atomicAdd(&counts[d], 1);
}

__global__ void dis_kernel(const float* __restrict__ deg, float* __restrict__ dis) {
    int i = blockIdx.x * blockDim.x + threadIdx.x;
    if (i < N_NODES) {
        float dg = deg[i];
        dis[i] = (dg > 0.f) ? (1.0f / sqrtf(dg)) : 0.f;
    }
}

// ---------- single-block exclusive scan of counts -> row_ptr ----------
__global__ __launch_bounds__(1024) void scan_kernel(const int* __restrict__ counts,
                                                    int* __restrict__ row_ptr) {
    __shared__ int psum[1024];
    const int T = 1024;
    const int chunk = (N_NODES + T - 1) / T;   // 49
    int t = threadIdx.x;
    int begin = t * chunk;
    int end = begin + chunk; if (end > N_NODES) end = N_NODES;
    int s = 0;
    for (int i = begin; i < end; ++i) s += counts[i];
    psum[t] = s;
    __syncthreads();
    for (int off = 1; off < T; off <<= 1) {
        int v = (t >= off) ? psum[t - off] : 0;
        __syncthreads();
        psum[t] += v;
        __syncthreads();
    }
    int base = (t == 0) ? 0 : psum[t - 1];
    for (int i = begin; i < end; ++i) {
        row_ptr[i] = base;
        base += counts[i];
    }
    if (t == T - 1) row_ptr[N_NODES] = base;
}

// ---------- fill CSR buckets: srcs + precomputed edge coefficients ----------
__global__ void fill_csr(const void* __restrict__ ei, const float* __restrict__ ew,
                         const float* __restrict__ dis, const int* __restrict__ row_ptr,
                         int* __restrict__ cursor, int* __restrict__ srcs,
                         float* __restrict__ coefs, const int* __restrict__ flag) {
    int e = blockIdx.x * blockDim.x + threadIdx.x;
    if (e >= N_EDGES) return;
    int is64 = *flag;
    int s = load_idx(ei, e, is64);
    int d = load_idx(ei, N_EDGES + e, is64);
    float coef = dis[s] * ew[e] * dis[d];
    int pos = row_ptr[d] + atomicAdd(&cursor[d], 1);
    srcs[pos] = s;
    coefs[pos] = coef;
}

// ---------- gather aggregation: one wave per node, register accumulation ----------
template <int C>
__global__ __launch_bounds__(256) void gather_agg(
    const float* __restrict__ x, const float* __restrict__ dis,
    const int* __restrict__ row_ptr, const int* __restrict__ srcs,
    const float* __restrict__ coefs, float* __restrict__ agg)
{
    constexpr int NV = C / 256;                  // float4s owned per lane
    int wid = threadIdx.x >> 6;
    int lane = threadIdx.x & 63;
    int node = blockIdx.x * 4 + wid;
    if (node >= N_NODES) return;

    float s = dis[node];
    s = s * s;                                   // self-loop norm
    const float4* xr = (const float4*)(x + (size_t)node * C);
    float4 acc[NV];
#pragma unroll
    for (int v = 0; v < NV; ++v) {
        float4 t = xr[lane + v * 64];
        acc[v] = make_float4(t.x * s, t.y * s, t.z * s, t.w * s);
    }

    int beg = row_ptr[node], end = row_ptr[node + 1];
    for (int j = beg; j < end; ++j) {
        int src = srcs[j];
        float c = coefs[j];
        const float4* xs = (const float4*)(x + (size_t)src * C);
#pragma unroll
        for (int v = 0; v < NV; ++v) {
            float4 t = xs[lane + v * 64];
            acc[v].x += c * t.x; acc[v].y += c * t.y;
            acc[v].z += c * t.z; acc[v].w += c * t.w;
        }
    }

    float4* ar = (float4*)(agg + (size_t)node * C);
#pragma unroll
    for (int v = 0; v < NV; ++v) ar[lane + v * 64] = acc[v];
}

// ---------- f32 GEMM: out[n,512] = X[n,K] @ W[512,K]^T + bias (optional PReLU) ----------
template <int K, bool PRELU>
__global__ __launch_bounds__(256) void gemm_kernel(
    const float* __restrict__ X, const float* __restrict__ Wt,
    const float* __restrict__ bias, const float* __restrict__ prelu_a,
    float* __restrict__ out, int n)
{
    __shared__ float As[32][68];
    __shared__ float Bs[32][68];
    const int tid = threadIdx.x;
    const int tx = tid & 15;
    const int ty = tid >> 4;
    const int row0 = blockIdx.x * 64;
    const int col0 = blockIdx.y * 64;
    float acc[4][4] = {};

    for (int k0 = 0; k0 < K; k0 += 32) {
        __syncthreads();
        for (int l = tid; l < 512; l += 256) {
            int r = l >> 3;
            int c4 = l & 7;
            float4 va;
            if (row0 + r < n)
                va = *(const float4*)(X + (size_t)(row0 + r) * K + k0 + c4 * 4);
            else
                va = make_float4(0.f, 0.f, 0.f, 0.f);
            As[c4 * 4 + 0][r] = va.x; As[c4 * 4 + 1][r] = va.y;
            As[c4 * 4 + 2][r] = va.z; As[c4 * 4 + 3][r] = va.w;
            float4 vb = *(const float4*)(Wt + (size_t)(col0 + r) * K + k0 + c4 * 4);
            Bs[c4 * 4 + 0][r] = vb.x; Bs[c4 * 4 + 1][r] = vb.y;
            Bs[c4 * 4 + 2][r] = vb.z; Bs[c4 * 4 + 3][r] = vb.w;
        }
        __syncthreads();
#pragma unroll
        for (int kk = 0; kk < 32; ++kk) {
            const float4 av = *(const float4*)&As[kk][ty * 4];
            const float4 bv = *(const float4*)&Bs[kk][tx * 4];
            const float a[4] = {av.x, av.y, av.z, av.w};
            const float b[4] = {bv.x, bv.y, bv.z, bv.w};
#pragma unroll
            for (int i = 0; i < 4; ++i)
#pragma unroll
                for (int j = 0; j < 4; ++j)
                    acc[i][j] += a[i] * b[j];
        }
    }

    const float ap = PRELU ? *prelu_a : 0.f;
    const float4 bv = *(const float4*)&bias[col0 + tx * 4];
    const float bb[4] = {bv.x, bv.y, bv.z, bv.w};
#pragma unroll
    for (int i = 0; i < 4; ++i) {
        int gr = row0 + ty * 4 + i;
        if (gr < n) {
            float4 o;
            float v0 = acc[i][0] + bb[0];
            float v1 = acc[i][1] + bb[1];
            float v2 = acc[i][2] + bb[2];
            float v3 = acc[i][3] + bb[3];
            if (PRELU) {
                v0 = (v0 >= 0.f) ? v0 : ap * v0;
                v1 = (v1 >= 0.f) ? v1 : ap * v1;
                v2 = (v2 >= 0.f) ? v2 : ap * v2;
                v3 = (v3 >= 0.f) ? v3 : ap * v3;
            }
            o.x = v0; o.y = v1; o.z = v2; o.w = v3;
            *(float4*)(out + (size_t)gr * HID + col0 + tx * 4) = o;
        }
    }
}

extern "C" void kernel_launch(void* const* d_in, const int* in_sizes, int n_in,
                              void* d_out, int out_size, void* d_ws, size_t ws_size,
                              hipStream_t stream) {
    const float* x  = (const float*)d_in[0];
    const void*  ei = d_in[1];
    const float* ew = (const float*)d_in[2];
    const float* W1 = (const float*)d_in[3];
    const float* b1 = (const float*)d_in[4];
    const float* W2 = (const float*)d_in[5];
    const float* b2 = (const float*)d_in[6];
    const float* pa = (const float*)d_in[7];
    float* out = (float*)d_out;

    float* ws      = (float*)d_ws;
    float* agg     = ws;                                   // 25.6M floats (102.4 MB)
    float* deg     = ws + (size_t)N_NODES * HID;
    float* dis     = deg + N_NODES;
    int*   flag    = (int*)(dis + N_NODES);
    int*   counts  = flag + 1;
    int*   cursor  = counts + N_NODES;
    int*   row_ptr = cursor + N_NODES;                     // N_NODES+1
    int*   srcs    = row_ptr + N_NODES + 1;                // N_EDGES
    float* coefs   = (float*)(srcs + N_EDGES);             // N_EDGES

    const int NB = (N_NODES + 255) / 256;
    const int EB = (N_EDGES + 255) / 256;

    // ----- CSR build (once, reused by both layers) -----
    detect_idx64<<<1, 256, 0, stream>>>((const unsigned int*)ei, flag);
    init_arrays<<<NB, 256, 0, stream>>>(deg, counts, cursor);
    deg_hist<<<EB, 256, 0, stream>>>(ei, ew, deg, counts, flag);
    dis_kernel<<<NB, 256, 0, stream>>>(deg, dis);
    scan_kernel<<<1, 1024, 0, stream>>>(counts, row_ptr);
    fill_csr<<<EB, 256, 0, stream>>>(ei, ew, dis, row_ptr, cursor, srcs, coefs, flag);

    // ----- layer 1: gather-aggregate x (256 ch) then GEMM(W1)+bias+PReLU -> d_out -----
    gather_agg<IN_CH><<<(N_NODES + 3) / 4, 256, 0, stream>>>(x, dis, row_ptr, srcs, coefs, agg);
    gemm_kernel<IN_CH, true><<<dim3((N_NODES + 63) / 64, HID / 64), 256, 0, stream>>>(
        agg, W1, b1, pa, out, N_NODES);

    // ----- layer 2: gather-aggregate p (512 ch) then GEMM(W2)+bias -> d_out -----
    gather_agg<HID><<<(N_NODES + 3) / 4, 256, 0, stream>>>(out, dis, row_ptr, srcs, coefs, agg);
    gemm_kernel<HID, false><<<dim3((N_NODES + 63) / 64, HID / 64), 256, 0, stream>>>(
        agg, W2, b2, pa, out, N_NODES);
}

// Round 3
// 510.072 us; speedup vs baseline: 7.3880x; 2.0524x over previous
//
#include <hip/hip_runtime.h>

#define N_NODES 50000
#define N_EDGES 300000
#define IN_CH 256
#define HID 512

typedef __bf16 bf16;
typedef bf16 bf16x8 __attribute__((ext_vector_type(8)));
typedef bf16 bf16x4 __attribute__((ext_vector_type(4)));
typedef float f32x4 __attribute__((ext_vector_type(4)));

__device__ __forceinline__ void load_lds16(const void* g, void* l) {
    __builtin_amdgcn_global_load_lds(
        (const __attribute__((address_space(1))) unsigned int*)g,
        (__attribute__((address_space(3))) unsigned int*)l, 16, 0, 0);
}

// ---------- index dtype detection (int32 vs int64, decided on-device) ----------
__global__ void detect_idx64(const unsigned int* __restrict__ ei, int* __restrict__ flag) {
    __shared__ int anynz;
    if (threadIdx.x == 0) anynz = 0;
    __syncthreads();
    int local = 0;
    for (int i = 1 + 2 * (int)threadIdx.x; i < 2 * N_EDGES; i += 2 * (int)blockDim.x)
        local |= (ei[i] != 0u);
    if (local) atomicOr(&anynz, 1);
    __syncthreads();
    if (threadIdx.x == 0) *flag = anynz ? 0 : 1;   // 1 => int64
}

__device__ __forceinline__ int load_idx(const void* ei, int i, int is64) {
    if (is64) return (int)((const long long*)ei)[i];
    return ((const int*)ei)[i];
}

// ---------- init ----------
__global__ void init_arrays(float* __restrict__ deg, int* __restrict__ counts,
                            int* __restrict__ cursor) {
    int i = blockIdx.x * blockDim.x + threadIdx.x;
    if (i < N_NODES) { deg[i] = 1.0f; counts[i] = 0; cursor[i] = 0; }
}

__global__ void deg_hist(const void* __restrict__ ei, const float* __restrict__ ew,
                         float* __restrict__ deg, int* __restrict__ counts,
                         const int* __restrict__ flag) {
    int e = blockIdx.x * blockDim.x + threadIdx.x;
    if (e >= N_EDGES) return;
    int is64 = *flag;
    int d = load_idx(ei, N_EDGES + e, is64);
    atomicAdd(&deg[d], ew[e]);
    atomicAdd(&counts[d], 1);
}

__global__ void dis_kernel(const float* __restrict__ deg, float* __restrict__ dis) {
    int i = blockIdx.x * blockDim.x + threadIdx.x;
    if (i < N_NODES) {
        float dg = deg[i];
        dis[i] = (dg > 0.f) ? (1.0f / sqrtf(dg)) : 0.f;
    }
}

// ---------- single-block exclusive scan of counts -> row_ptr ----------
__global__ __launch_bounds__(1024) void scan_kernel(const int* __restrict__ counts,
                                                    int* __restrict__ row_ptr) {
    __shared__ int psum[1024];
    const int T = 1024;
    const int chunk = (N_NODES + T - 1) / T;
    int t = threadIdx.x;
    int begin = t * chunk;
    int end = begin + chunk; if (end > N_NODES) end = N_NODES;
    int s = 0;
    for (int i = begin; i < end; ++i) s += counts[i];
    psum[t] = s;
    __syncthreads();
    for (int off = 1; off < T; off <<= 1) {
        int v = (t >= off) ? psum[t - off] : 0;
        __syncthreads();
        psum[t] += v;
        __syncthreads();
    }
    int base = (t == 0) ? 0 : psum[t - 1];
    for (int i = begin; i < end; ++i) {
        row_ptr[i] = base;
        base += counts[i];
    }
    if (t == T - 1) row_ptr[N_NODES] = base;
}

__global__ void fill_csr(const void* __restrict__ ei, const float* __restrict__ ew,
                         const float* __restrict__ dis, const int* __restrict__ row_ptr,
                         int* __restrict__ cursor, int* __restrict__ srcs,
                         float* __restrict__ coefs, const int* __restrict__ flag) {
    int e = blockIdx.x * blockDim.x + threadIdx.x;
    if (e >= N_EDGES) return;
    int is64 = *flag;
    int s = load_idx(ei, e, is64);
    int d = load_idx(ei, N_EDGES + e, is64);
    float coef = dis[s] * ew[e] * dis[d];
    int pos = row_ptr[d] + atomicAdd(&cursor[d], 1);
    srcs[pos] = s;
    coefs[pos] = coef;
}

// ---------- f32 -> bf16 convert ----------
__global__ void f2b_kernel(const float* __restrict__ s, bf16* __restrict__ d, int n) {
    int i = blockIdx.x * blockDim.x + threadIdx.x;
    if (i < n) d[i] = (bf16)s[i];
}

// ---------- gather aggregation, f32 input (layer 1), bf16 output ----------
__global__ __launch_bounds__(256) void gather_agg_f32(
    const float* __restrict__ x, const float* __restrict__ dis,
    const int* __restrict__ row_ptr, const int* __restrict__ srcs,
    const float* __restrict__ coefs, bf16* __restrict__ agg)
{
    int wid = threadIdx.x >> 6;
    int lane = threadIdx.x & 63;
    int node = blockIdx.x * 4 + wid;
    if (node >= N_NODES) return;

    float s = dis[node];
    s = s * s;
    float4 t0 = ((const float4*)(x + (size_t)node * IN_CH))[lane];
    float acc0 = s * t0.x, acc1 = s * t0.y, acc2 = s * t0.z, acc3 = s * t0.w;

    int beg = row_ptr[node], end = row_ptr[node + 1];
    for (int j = beg; j < end; ++j) {
        int src = srcs[j];
        float c = coefs[j];
        float4 t = ((const float4*)(x + (size_t)src * IN_CH))[lane];
        acc0 += c * t.x; acc1 += c * t.y; acc2 += c * t.z; acc3 += c * t.w;
    }
    bf16x4 o;
    o[0] = (bf16)acc0; o[1] = (bf16)acc1; o[2] = (bf16)acc2; o[3] = (bf16)acc3;
    *(bf16x4*)(agg + (size_t)node * IN_CH + lane * 4) = o;
}

// ---------- gather aggregation, bf16 input (layer 2), bf16 output ----------
__global__ __launch_bounds__(256) void gather_agg_bf16(
    const bf16* __restrict__ p, const float* __restrict__ dis,
    const int* __restrict__ row_ptr, const int* __restrict__ srcs,
    const float* __restrict__ coefs, bf16* __restrict__ agg)
{
    int wid = threadIdx.x >> 6;
    int lane = threadIdx.x & 63;
    int node = blockIdx.x * 4 + wid;
    if (node >= N_NODES) return;

    float s = dis[node];
    s = s * s;
    float acc[8];
    bf16x8 t0 = *(const bf16x8*)(p + (size_t)node * HID + lane * 8);
#pragma unroll
    for (int i = 0; i < 8; ++i) acc[i] = s * (float)t0[i];

    int beg = row_ptr[node], end = row_ptr[node + 1];
    for (int j = beg; j < end; ++j) {
        int src = srcs[j];
        float c = coefs[j];
        bf16x8 t = *(const bf16x8*)(p + (size_t)src * HID + lane * 8);
#pragma unroll
        for (int i = 0; i < 8; ++i) acc[i] += c * (float)t[i];
    }
    bf16x8 o;
#pragma unroll
    for (int i = 0; i < 8; ++i) o[i] = (bf16)acc[i];
    *(bf16x8*)(agg + (size_t)node * HID + lane * 8) = o;
}

// ---------- MFMA bf16 GEMM: out[n,512] = X[n,K] @ Wt[512,K]^T + bias ----------
// 128x128 tile, BK=32, 4 waves (2x2), 16x16x32 MFMA, global_load_lds staging.
template <int K, bool PRELU, bool OUT_BF16>
__global__ __launch_bounds__(256) void gemm_mfma(
    const bf16* __restrict__ X, const bf16* __restrict__ Wt,
    const float* __restrict__ bias, const float* __restrict__ prelu_a,
    void* __restrict__ outv, int n)
{
    __shared__ __align__(16) bf16 As[128 * 32];
    __shared__ __align__(16) bf16 Bs[128 * 32];
    const int tid = threadIdx.x;
    const int lane = tid & 63;
    const int wid = tid >> 6;
    const int wr = wid >> 1, wc = wid & 1;
    const int row0 = blockIdx.x * 128;
    const int col0 = blockIdx.y * 128;

    f32x4 acc[4][4] = {};

    for (int k0 = 0; k0 < K; k0 += 32) {
        // stage 128x32 of A and B into linear LDS (4x global_load_lds x16B per thread)
#pragma unroll
        for (int h = 0; h < 2; ++h) {
            int seg = tid + h * 256;          // 0..511
            int r = seg >> 2;                 // 0..127
            int sl = seg & 3;                 // 16B segment within 64B row
            int ra = row0 + r; if (ra >= n) ra = n - 1;
            load_lds16(X + (size_t)ra * K + k0 + sl * 8, &As[seg * 8]);
            load_lds16(Wt + (size_t)(col0 + r) * K + k0 + sl * 8, &Bs[seg * 8]);
        }
        __syncthreads();   // compiler drains vmcnt before s_barrier -> LDS ready

        bf16x8 af[4], bfr[4];
#pragma unroll
        for (int m = 0; m < 4; ++m) {
            int r = wr * 64 + m * 16 + (lane & 15);
            af[m] = *(const bf16x8*)&As[r * 32 + (lane >> 4) * 8];
        }
#pragma unroll
        for (int nn = 0; nn < 4; ++nn) {
            int r = wc * 64 + nn * 16 + (lane & 15);
            bfr[nn] = *(const bf16x8*)&Bs[r * 32 + (lane >> 4) * 8];
        }
#pragma unroll
        for (int m = 0; m < 4; ++m)
#pragma unroll
            for (int nn = 0; nn < 4; ++nn)
                acc[m][nn] = __builtin_amdgcn_mfma_f32_16x16x32_bf16(
                    af[m], bfr[nn], acc[m][nn], 0, 0, 0);
        __syncthreads();   // all reads done before next stage overwrites
    }

    const float ap = PRELU ? *prelu_a : 0.f;
#pragma unroll
    for (int m = 0; m < 4; ++m) {
        int gr_base = row0 + wr * 64 + m * 16 + (lane >> 4) * 4;
#pragma unroll
        for (int nn = 0; nn < 4; ++nn) {
            int gc = col0 + wc * 64 + nn * 16 + (lane & 15);
            float bv = bias[gc];
#pragma unroll
            for (int j = 0; j < 4; ++j) {
                int gr = gr_base + j;
                if (gr < n) {
                    float v = acc[m][nn][j] + bv;
                    if (PRELU) v = (v >= 0.f) ? v : ap * v;
                    if (OUT_BF16) ((bf16*)outv)[(size_t)gr * HID + gc] = (bf16)v;
                    else         ((float*)outv)[(size_t)gr * HID + gc] = v;
                }
            }
        }
    }
}

extern "C" void kernel_launch(void* const* d_in, const int* in_sizes, int n_in,
                              void* d_out, int out_size, void* d_ws, size_t ws_size,
                              hipStream_t stream) {
    const float* x  = (const float*)d_in[0];
    const void*  ei = d_in[1];
    const float* ew = (const float*)d_in[2];
    const float* W1 = (const float*)d_in[3];
    const float* b1 = (const float*)d_in[4];
    const float* W2 = (const float*)d_in[5];
    const float* b2 = (const float*)d_in[6];
    const float* pa = (const float*)d_in[7];

    char* base = (char*)d_ws;
    bf16*  aggb    = (bf16*)base;                          // 51.2 MB (L1 uses first 25.6)
    bf16*  W1b     = (bf16*)(base + (size_t)N_NODES * HID * 2);
    bf16*  W2b     = W1b + HID * IN_CH;
    float* deg     = (float*)(W2b + HID * HID);
    float* dis     = deg + N_NODES;
    int*   flag    = (int*)(dis + N_NODES);
    int*   counts  = flag + 1;
    int*   cursor  = counts + N_NODES;
    int*   row_ptr = cursor + N_NODES;                     // N_NODES+1
    int*   srcs    = row_ptr + N_NODES + 1;                // N_EDGES
    float* coefs   = (float*)(srcs + N_EDGES);             // N_EDGES

    bf16* p_bf = (bf16*)d_out;   // layer-1 output lives (as bf16) in d_out, consumed before GEMM2 writes f32

    const int NB = (N_NODES + 255) / 256;
    const int EB = (N_EDGES + 255) / 256;

    // ----- CSR build (once, reused by both layers) -----
    detect_idx64<<<1, 256, 0, stream>>>((const unsigned int*)ei, flag);
    init_arrays<<<NB, 256, 0, stream>>>(deg, counts, cursor);
    deg_hist<<<EB, 256, 0, stream>>>(ei, ew, deg, counts, flag);
    dis_kernel<<<NB, 256, 0, stream>>>(deg, dis);
    scan_kernel<<<1, 1024, 0, stream>>>(counts, row_ptr);
    fill_csr<<<EB, 256, 0, stream>>>(ei, ew, dis, row_ptr, cursor, srcs, coefs, flag);

    // ----- weight conversion -----
    f2b_kernel<<<(HID * IN_CH + 255) / 256, 256, 0, stream>>>(W1, W1b, HID * IN_CH);
    f2b_kernel<<<(HID * HID + 255) / 256, 256, 0, stream>>>(W2, W2b, HID * HID);

    // ----- layer 1: gather x (f32 in, bf16 out) -> MFMA GEMM + bias + PReLU -> bf16 p -----
    gather_agg_f32<<<(N_NODES + 3) / 4, 256, 0, stream>>>(x, dis, row_ptr, srcs, coefs, aggb);
    gemm_mfma<IN_CH, true, true><<<dim3((N_NODES + 127) / 128, HID / 128), 256, 0, stream>>>(
        aggb, W1b, b1, pa, p_bf, N_NODES);

    // ----- layer 2: gather p (bf16 in/out) -> MFMA GEMM + bias -> f32 d_out -----
    gather_agg_bf16<<<(N_NODES + 3) / 4, 256, 0, stream>>>(p_bf, dis, row_ptr, srcs, coefs, aggb);
    gemm_mfma<HID, false, false><<<dim3((N_NODES + 127) / 128, HID / 128), 256, 0, stream>>>(
        aggb, W2b, b2, pa, (float*)d_out, N_NODES);
}

// Round 4
// 378.539 us; speedup vs baseline: 9.9552x; 1.3475x over previous
//
#include <hip/hip_runtime.h>

#define N_NODES 50000
#define N_EDGES 300000
#define IN_CH 256
#define HID 512

typedef __bf16 bf16;
typedef bf16 bf16x8 __attribute__((ext_vector_type(8)));
typedef bf16 bf16x4 __attribute__((ext_vector_type(4)));
typedef float f32x4 __attribute__((ext_vector_type(4)));

__device__ __forceinline__ void load_lds16(const void* g, void* l) {
    __builtin_amdgcn_global_load_lds(
        (const __attribute__((address_space(1))) unsigned int*)g,
        (__attribute__((address_space(3))) unsigned int*)l, 16, 0, 0);
}

// ---------- index dtype detection (int32 vs int64), parallel ----------
__global__ void init_flag(int* __restrict__ flag) {
    if (threadIdx.x == 0 && blockIdx.x == 0) *flag = 1;   // assume int64
}

// If any odd 32-bit word (high half of an int64) is nonzero -> indices are int32.
__global__ void detect_idx64_par(const unsigned int* __restrict__ ei, int* __restrict__ flag) {
    int stride = gridDim.x * blockDim.x;
    int i = blockIdx.x * blockDim.x + threadIdx.x;
    int local = 0;
    for (int idx = 1 + 2 * i; idx < 2 * N_EDGES; idx += 2 * stride)
        local |= (ei[idx] != 0u);
    if (__any(local)) {
        if ((threadIdx.x & 63) == 0) atomicAnd(flag, 0);
    }
}

__device__ __forceinline__ int load_idx(const void* ei, int i, int is64) {
    if (is64) return (int)((const long long*)ei)[i];
    return ((const int*)ei)[i];
}

// ---------- init ----------
__global__ void init_arrays(float* __restrict__ deg, int* __restrict__ counts,
                            int* __restrict__ cursor) {
    int i = blockIdx.x * blockDim.x + threadIdx.x;
    if (i < N_NODES) { deg[i] = 1.0f; counts[i] = 0; cursor[i] = 0; }
}

__global__ void deg_hist(const void* __restrict__ ei, const float* __restrict__ ew,
                         float* __restrict__ deg, int* __restrict__ counts,
                         const int* __restrict__ flag) {
    int e = blockIdx.x * blockDim.x + threadIdx.x;
    if (e >= N_EDGES) return;
    int is64 = *flag;
    int d = load_idx(ei, N_EDGES + e, is64);
    atomicAdd(&deg[d], ew[e]);
    atomicAdd(&counts[d], 1);
}

__global__ void dis_kernel(const float* __restrict__ deg, float* __restrict__ dis) {
    int i = blockIdx.x * blockDim.x + threadIdx.x;
    if (i < N_NODES) {
        float dg = deg[i];
        dis[i] = (dg > 0.f) ? (1.0f / sqrtf(dg)) : 0.f;
    }
}

// ---------- single-block exclusive scan of counts -> row_ptr ----------
__global__ __launch_bounds__(1024) void scan_kernel(const int* __restrict__ counts,
                                                    int* __restrict__ row_ptr) {
    __shared__ int psum[1024];
    const int T = 1024;
    const int chunk = (N_NODES + T - 1) / T;
    int t = threadIdx.x;
    int begin = t * chunk;
    int end = begin + chunk; if (end > N_NODES) end = N_NODES;
    int s = 0;
    for (int i = begin; i < end; ++i) s += counts[i];
    psum[t] = s;
    __syncthreads();
    for (int off = 1; off < T; off <<= 1) {
        int v = (t >= off) ? psum[t - off] : 0;
        __syncthreads();
        psum[t] += v;
        __syncthreads();
    }
    int base = (t == 0) ? 0 : psum[t - 1];
    for (int i = begin; i < end; ++i) {
        row_ptr[i] = base;
        base += counts[i];
    }
    if (t == T - 1) row_ptr[N_NODES] = base;
}

__global__ void fill_csr(const void* __restrict__ ei, const float* __restrict__ ew,
                         const float* __restrict__ dis, const int* __restrict__ row_ptr,
                         int* __restrict__ cursor, int* __restrict__ srcs,
                         float* __restrict__ coefs, const int* __restrict__ flag) {
    int e = blockIdx.x * blockDim.x + threadIdx.x;
    if (e >= N_EDGES) return;
    int is64 = *flag;
    int s = load_idx(ei, e, is64);
    int d = load_idx(ei, N_EDGES + e, is64);
    float coef = dis[s] * ew[e] * dis[d];
    int pos = row_ptr[d] + atomicAdd(&cursor[d], 1);
    srcs[pos] = s;
    coefs[pos] = coef;
}

// ---------- f32 -> bf16 convert ----------
__global__ void f2b_kernel(const float* __restrict__ s, bf16* __restrict__ d, int n) {
    int i = blockIdx.x * blockDim.x + threadIdx.x;
    if (i < n) d[i] = (bf16)s[i];
}

// ---------- gather aggregation, f32 input (layer 1), bf16 output ----------
__global__ __launch_bounds__(256) void gather_agg_f32(
    const float* __restrict__ x, const float* __restrict__ dis,
    const int* __restrict__ row_ptr, const int* __restrict__ srcs,
    const float* __restrict__ coefs, bf16* __restrict__ agg)
{
    int wid = threadIdx.x >> 6;
    int lane = threadIdx.x & 63;
    int node = blockIdx.x * 4 + wid;
    if (node >= N_NODES) return;

    float s = dis[node];
    s = s * s;
    float4 t0 = ((const float4*)(x + (size_t)node * IN_CH))[lane];
    float acc0 = s * t0.x, acc1 = s * t0.y, acc2 = s * t0.z, acc3 = s * t0.w;

    int beg = row_ptr[node], end = row_ptr[node + 1];
    for (int j = beg; j < end; ++j) {
        int src = srcs[j];
        float c = coefs[j];
        float4 t = ((const float4*)(x + (size_t)src * IN_CH))[lane];
        acc0 += c * t.x; acc1 += c * t.y; acc2 += c * t.z; acc3 += c * t.w;
    }
    bf16x4 o;
    o[0] = (bf16)acc0; o[1] = (bf16)acc1; o[2] = (bf16)acc2; o[3] = (bf16)acc3;
    *(bf16x4*)(agg + (size_t)node * IN_CH + lane * 4) = o;
}

// ---------- gather aggregation, bf16 input (layer 2), bf16 output ----------
__global__ __launch_bounds__(256) void gather_agg_bf16(
    const bf16* __restrict__ p, const float* __restrict__ dis,
    const int* __restrict__ row_ptr, const int* __restrict__ srcs,
    const float* __restrict__ coefs, bf16* __restrict__ agg)
{
    int wid = threadIdx.x >> 6;
    int lane = threadIdx.x & 63;
    int node = blockIdx.x * 4 + wid;
    if (node >= N_NODES) return;

    float s = dis[node];
    s = s * s;
    float acc[8];
    bf16x8 t0 = *(const bf16x8*)(p + (size_t)node * HID + lane * 8);
#pragma unroll
    for (int i = 0; i < 8; ++i) acc[i] = s * (float)t0[i];

    int beg = row_ptr[node], end = row_ptr[node + 1];
    for (int j = beg; j < end; ++j) {
        int src = srcs[j];
        float c = coefs[j];
        bf16x8 t = *(const bf16x8*)(p + (size_t)src * HID + lane * 8);
#pragma unroll
        for (int i = 0; i < 8; ++i) acc[i] += c * (float)t[i];
    }
    bf16x8 o;
#pragma unroll
    for (int i = 0; i < 8; ++i) o[i] = (bf16)acc[i];
    *(bf16x8*)(agg + (size_t)node * HID + lane * 8) = o;
}

// ---------- MFMA bf16 GEMM: out[n,512] = X[n,K] @ Wt[512,K]^T + bias ----------
// 128x128 tile, BK=32, 4 waves (2x2), 16x16x32 MFMA, global_load_lds staging.
template <int K, bool PRELU, bool OUT_BF16>
__global__ __launch_bounds__(256) void gemm_mfma(
    const bf16* __restrict__ X, const bf16* __restrict__ Wt,
    const float* __restrict__ bias, const float* __restrict__ prelu_a,
    void* __restrict__ outv, int n)
{
    __shared__ __align__(16) bf16 As[128 * 32];
    __shared__ __align__(16) bf16 Bs[128 * 32];
    const int tid = threadIdx.x;
    const int lane = tid & 63;
    const int wid = tid >> 6;
    const int wr = wid >> 1, wc = wid & 1;
    const int row0 = blockIdx.x * 128;
    const int col0 = blockIdx.y * 128;

    f32x4 acc[4][4] = {};

    for (int k0 = 0; k0 < K; k0 += 32) {
#pragma unroll
        for (int h = 0; h < 2; ++h) {
            int seg = tid + h * 256;          // 0..511
            int r = seg >> 2;                 // 0..127
            int sl = seg & 3;                 // 16B segment within 64B row
            int ra = row0 + r; if (ra >= n) ra = n - 1;
            load_lds16(X + (size_t)ra * K + k0 + sl * 8, &As[seg * 8]);
            load_lds16(Wt + (size_t)(col0 + r) * K + k0 + sl * 8, &Bs[seg * 8]);
        }
        __syncthreads();

        bf16x8 af[4], bfr[4];
#pragma unroll
        for (int m = 0; m < 4; ++m) {
            int r = wr * 64 + m * 16 + (lane & 15);
            af[m] = *(const bf16x8*)&As[r * 32 + (lane >> 4) * 8];
        }
#pragma unroll
        for (int nn = 0; nn < 4; ++nn) {
            int r = wc * 64 + nn * 16 + (lane & 15);
            bfr[nn] = *(const bf16x8*)&Bs[r * 32 + (lane >> 4) * 8];
        }
#pragma unroll
        for (int m = 0; m < 4; ++m)
#pragma unroll
            for (int nn = 0; nn < 4; ++nn)
                acc[m][nn] = __builtin_amdgcn_mfma_f32_16x16x32_bf16(
                    af[m], bfr[nn], acc[m][nn], 0, 0, 0);
        __syncthreads();
    }

    const float ap = PRELU ? *prelu_a : 0.f;
#pragma unroll
    for (int m = 0; m < 4; ++m) {
        int gr_base = row0 + wr * 64 + m * 16 + (lane >> 4) * 4;
#pragma unroll
        for (int nn = 0; nn < 4; ++nn) {
            int gc = col0 + wc * 64 + nn * 16 + (lane & 15);
            float bv = bias[gc];
#pragma unroll
            for (int j = 0; j < 4; ++j) {
                int gr = gr_base + j;
                if (gr < n) {
                    float v = acc[m][nn][j] + bv;
                    if (PRELU) v = (v >= 0.f) ? v : ap * v;
                    if (OUT_BF16) ((bf16*)outv)[(size_t)gr * HID + gc] = (bf16)v;
                    else         ((float*)outv)[(size_t)gr * HID + gc] = v;
                }
            }
        }
    }
}

extern "C" void kernel_launch(void* const* d_in, const int* in_sizes, int n_in,
                              void* d_out, int out_size, void* d_ws, size_t ws_size,
                              hipStream_t stream) {
    const float* x  = (const float*)d_in[0];
    const void*  ei = d_in[1];
    const float* ew = (const float*)d_in[2];
    const float* W1 = (const float*)d_in[3];
    const float* b1 = (const float*)d_in[4];
    const float* W2 = (const float*)d_in[5];
    const float* b2 = (const float*)d_in[6];
    const float* pa = (const float*)d_in[7];

    char* base = (char*)d_ws;
    bf16*  aggb    = (bf16*)base;                          // 51.2 MB (L1 uses first 25.6)
    bf16*  W1b     = (bf16*)(base + (size_t)N_NODES * HID * 2);
    bf16*  W2b     = W1b + HID * IN_CH;
    float* deg     = (float*)(W2b + HID * HID);
    float* dis     = deg + N_NODES;
    int*   flag    = (int*)(dis + N_NODES);
    int*   counts  = flag + 1;
    int*   cursor  = counts + N_NODES;
    int*   row_ptr = cursor + N_NODES;                     // N_NODES+1
    int*   srcs    = row_ptr + N_NODES + 1;                // N_EDGES
    float* coefs   = (float*)(srcs + N_EDGES);             // N_EDGES

    bf16* p_bf = (bf16*)d_out;   // layer-1 output lives (as bf16) in d_out, consumed before GEMM2 writes f32

    const int NB = (N_NODES + 255) / 256;
    const int EB = (N_EDGES + 255) / 256;

    // ----- CSR build (once, reused by both layers) -----
    init_flag<<<1, 64, 0, stream>>>(flag);
    detect_idx64_par<<<512, 256, 0, stream>>>((const unsigned int*)ei, flag);
    init_arrays<<<NB, 256, 0, stream>>>(deg, counts, cursor);
    deg_hist<<<EB, 256, 0, stream>>>(ei, ew, deg, counts, flag);
    dis_kernel<<<NB, 256, 0, stream>>>(deg, dis);
    scan_kernel<<<1, 1024, 0, stream>>>(counts, row_ptr);
    fill_csr<<<EB, 256, 0, stream>>>(ei, ew, dis, row_ptr, cursor, srcs, coefs, flag);

    // ----- weight conversion -----
    f2b_kernel<<<(HID * IN_CH + 255) / 256, 256, 0, stream>>>(W1, W1b, HID * IN_CH);
    f2b_kernel<<<(HID * HID + 255) / 256, 256, 0, stream>>>(W2, W2b, HID * HID);

    // ----- layer 1: gather x (f32 in, bf16 out) -> MFMA GEMM + bias + PReLU -> bf16 p -----
    gather_agg_f32<<<(N_NODES + 3) / 4, 256, 0, stream>>>(x, dis, row_ptr, srcs, coefs, aggb);
    gemm_mfma<IN_CH, true, true><<<dim3((N_NODES + 127) / 128, HID / 128), 256, 0, stream>>>(
        aggb, W1b, b1, pa, p_bf, N_NODES);

    // ----- layer 2: gather p (bf16 in/out) -> MFMA GEMM + bias -> f32 d_out -----
    gather_agg_bf16<<<(N_NODES + 3) / 4, 256, 0, stream>>>(p_bf, dis, row_ptr, srcs, coefs, aggb);
    gemm_mfma<HID, false, false><<<dim3((N_NODES + 127) / 128, HID / 128), 256, 0, stream>>>(
        aggb, W2b, b2, pa, (float*)d_out, N_NODES);
}

// Round 5
// 306.880 us; speedup vs baseline: 12.2798x; 1.2335x over previous
//
#include <hip/hip_runtime.h>

#define N_NODES 50000
#define N_EDGES 300000
#define IN_CH 256
#define HID 512
#define SCAN_NBLK ((N_NODES + 255) / 256)   // 196

typedef __bf16 bf16;
typedef bf16 bf16x8 __attribute__((ext_vector_type(8)));
typedef bf16 bf16x4 __attribute__((ext_vector_type(4)));
typedef float f32x4 __attribute__((ext_vector_type(4)));

__device__ __forceinline__ void load_lds16(const void* g, void* l) {
    __builtin_amdgcn_global_load_lds(
        (const __attribute__((address_space(1))) unsigned int*)g,
        (__attribute__((address_space(3))) unsigned int*)l, 16, 0, 0);
}

// ---------- index dtype detection (int32 vs int64), parallel ----------
// If any odd 32-bit word (high half of an int64) is nonzero -> indices are int32.
__global__ void detect_idx64_par(const unsigned int* __restrict__ ei, int* __restrict__ flag) {
    int stride = gridDim.x * blockDim.x;
    int i = blockIdx.x * blockDim.x + threadIdx.x;
    int local = 0;
    for (int idx = 1 + 2 * i; idx < 2 * N_EDGES; idx += 2 * stride)
        local |= (ei[idx] != 0u);
    if (__any(local)) {
        if ((threadIdx.x & 63) == 0) atomicAnd(flag, 0);
    }
}

__device__ __forceinline__ int load_idx(const void* ei, int i, int is64) {
    if (is64) return (int)((const long long*)ei)[i];
    return ((const int*)ei)[i];
}

// ---------- init (deg=1 self-loop, histogram+cursor=0, flag=1) ----------
__global__ void init_arrays(float* __restrict__ deg, int* __restrict__ counts,
                            int* __restrict__ cursor, int* __restrict__ flag) {
    int i = blockIdx.x * blockDim.x + threadIdx.x;
    if (i == 0) *flag = 1;   // assume int64 until detector clears it
    if (i < N_NODES) { deg[i] = 1.0f; counts[i] = 0; cursor[i] = 0; }
}

__global__ void deg_hist(const void* __restrict__ ei, const float* __restrict__ ew,
                         float* __restrict__ deg, int* __restrict__ counts,
                         const int* __restrict__ flag) {
    int e = blockIdx.x * blockDim.x + threadIdx.x;
    if (e >= N_EDGES) return;
    int is64 = *flag;
    int d = load_idx(ei, N_EDGES + e, is64);
    atomicAdd(&deg[d], ew[e]);
    atomicAdd(&counts[d], 1);
}

// ---------- parallel scan, phase A: block-local scan + dis (fused) ----------
__global__ __launch_bounds__(256) void scan_partial(
    const int* __restrict__ counts, const float* __restrict__ deg,
    float* __restrict__ dis, int* __restrict__ row_ptr, int* __restrict__ partials)
{
    __shared__ int psum[256];
    int t = threadIdx.x;
    int i = blockIdx.x * 256 + t;
    if (i < N_NODES) {
        float dg = deg[i];
        dis[i] = (dg > 0.f) ? (1.0f / sqrtf(dg)) : 0.f;
    }
    int c = (i < N_NODES) ? counts[i] : 0;
    psum[t] = c;
    __syncthreads();
#pragma unroll
    for (int off = 1; off < 256; off <<= 1) {
        int v = (t >= off) ? psum[t - off] : 0;
        __syncthreads();
        psum[t] += v;
        __syncthreads();
    }
    if (i < N_NODES) row_ptr[i] = psum[t] - c;       // block-local exclusive prefix
    if (t == 255) partials[blockIdx.x] = psum[255];  // block total
}

// ---------- phase B: scan the 196 block totals (single tiny block) ----------
__global__ __launch_bounds__(256) void scan_partials(int* __restrict__ partials,
                                                     int* __restrict__ row_ptr) {
    __shared__ int psum[256];
    int t = threadIdx.x;
    int p = (t < SCAN_NBLK) ? partials[t] : 0;
    psum[t] = p;
    __syncthreads();
#pragma unroll
    for (int off = 1; off < 256; off <<= 1) {
        int v = (t >= off) ? psum[t - off] : 0;
        __syncthreads();
        psum[t] += v;
        __syncthreads();
    }
    if (t < SCAN_NBLK) partials[t] = psum[t] - p;    // exclusive block offsets
    if (t == 255) row_ptr[N_NODES] = psum[255];      // total (= N_EDGES)
}

// ---------- phase C: add block offsets ----------
__global__ void scan_add(int* __restrict__ row_ptr, const int* __restrict__ partials) {
    int i = blockIdx.x * 256 + threadIdx.x;
    if (i < N_NODES) row_ptr[i] += partials[blockIdx.x];
}

__global__ void fill_csr(const void* __restrict__ ei, const float* __restrict__ ew,
                         const float* __restrict__ dis, const int* __restrict__ row_ptr,
                         int* __restrict__ cursor, int* __restrict__ srcs,
                         float* __restrict__ coefs, const int* __restrict__ flag) {
    int e = blockIdx.x * blockDim.x + threadIdx.x;
    if (e >= N_EDGES) return;
    int is64 = *flag;
    int s = load_idx(ei, e, is64);
    int d = load_idx(ei, N_EDGES + e, is64);
    float coef = dis[s] * ew[e] * dis[d];
    int pos = row_ptr[d] + atomicAdd(&cursor[d], 1);
    srcs[pos] = s;
    coefs[pos] = coef;
}

// ---------- f32 -> bf16 convert, both weight matrices in one launch ----------
__global__ void f2b2_kernel(const float* __restrict__ a, bf16* __restrict__ da, int na,
                            const float* __restrict__ b, bf16* __restrict__ db, int nb) {
    int i = blockIdx.x * blockDim.x + threadIdx.x;
    if (i < na) da[i] = (bf16)a[i];
    else if (i - na < nb) db[i - na] = (bf16)b[i - na];
}

// ---------- gather aggregation, f32 input (layer 1), bf16 output ----------
__global__ __launch_bounds__(256) void gather_agg_f32(
    const float* __restrict__ x, const float* __restrict__ dis,
    const int* __restrict__ row_ptr, const int* __restrict__ srcs,
    const float* __restrict__ coefs, bf16* __restrict__ agg)
{
    int wid = threadIdx.x >> 6;
    int lane = threadIdx.x & 63;
    int node = blockIdx.x * 4 + wid;
    if (node >= N_NODES) return;

    float s = dis[node];
    s = s * s;
    float4 t0 = ((const float4*)(x + (size_t)node * IN_CH))[lane];
    float acc0 = s * t0.x, acc1 = s * t0.y, acc2 = s * t0.z, acc3 = s * t0.w;

    int beg = row_ptr[node], end = row_ptr[node + 1];
    for (int j = beg; j < end; ++j) {
        int src = srcs[j];
        float c = coefs[j];
        float4 t = ((const float4*)(x + (size_t)src * IN_CH))[lane];
        acc0 += c * t.x; acc1 += c * t.y; acc2 += c * t.z; acc3 += c * t.w;
    }
    bf16x4 o;
    o[0] = (bf16)acc0; o[1] = (bf16)acc1; o[2] = (bf16)acc2; o[3] = (bf16)acc3;
    *(bf16x4*)(agg + (size_t)node * IN_CH + lane * 4) = o;
}

// ---------- gather aggregation, bf16 input (layer 2), bf16 output ----------
__global__ __launch_bounds__(256) void gather_agg_bf16(
    const bf16* __restrict__ p, const float* __restrict__ dis,
    const int* __restrict__ row_ptr, const int* __restrict__ srcs,
    const float* __restrict__ coefs, bf16* __restrict__ agg)
{
    int wid = threadIdx.x >> 6;
    int lane = threadIdx.x & 63;
    int node = blockIdx.x * 4 + wid;
    if (node >= N_NODES) return;

    float s = dis[node];
    s = s * s;
    float acc[8];
    bf16x8 t0 = *(const bf16x8*)(p + (size_t)node * HID + lane * 8);
#pragma unroll
    for (int i = 0; i < 8; ++i) acc[i] = s * (float)t0[i];

    int beg = row_ptr[node], end = row_ptr[node + 1];
    for (int j = beg; j < end; ++j) {
        int src = srcs[j];
        float c = coefs[j];
        bf16x8 t = *(const bf16x8*)(p + (size_t)src * HID + lane * 8);
#pragma unroll
        for (int i = 0; i < 8; ++i) acc[i] += c * (float)t[i];
    }
    bf16x8 o;
#pragma unroll
    for (int i = 0; i < 8; ++i) o[i] = (bf16)acc[i];
    *(bf16x8*)(agg + (size_t)node * HID + lane * 8) = o;
}

// ---------- MFMA bf16 GEMM: out[n,512] = X[n,K] @ Wt[512,K]^T + bias ----------
template <int K, bool PRELU, bool OUT_BF16>
__global__ __launch_bounds__(256) void gemm_mfma(
    const bf16* __restrict__ X, const bf16* __restrict__ Wt,
    const float* __restrict__ bias, const float* __restrict__ prelu_a,
    void* __restrict__ outv, int n)
{
    __shared__ __align__(16) bf16 As[128 * 32];
    __shared__ __align__(16) bf16 Bs[128 * 32];
    const int tid = threadIdx.x;
    const int lane = tid & 63;
    const int wid = tid >> 6;
    const int wr = wid >> 1, wc = wid & 1;
    const int row0 = blockIdx.x * 128;
    const int col0 = blockIdx.y * 128;

    f32x4 acc[4][4] = {};

    for (int k0 = 0; k0 < K; k0 += 32) {
#pragma unroll
        for (int h = 0; h < 2; ++h) {
            int seg = tid + h * 256;
            int r = seg >> 2;
            int sl = seg & 3;
            int ra = row0 + r; if (ra >= n) ra = n - 1;
            load_lds16(X + (size_t)ra * K + k0 + sl * 8, &As[seg * 8]);
            load_lds16(Wt + (size_t)(col0 + r) * K + k0 + sl * 8, &Bs[seg * 8]);
        }
        __syncthreads();

        bf16x8 af[4], bfr[4];
#pragma unroll
        for (int m = 0; m < 4; ++m) {
            int r = wr * 64 + m * 16 + (lane & 15);
            af[m] = *(const bf16x8*)&As[r * 32 + (lane >> 4) * 8];
        }
#pragma unroll
        for (int nn = 0; nn < 4; ++nn) {
            int r = wc * 64 + nn * 16 + (lane & 15);
            bfr[nn] = *(const bf16x8*)&Bs[r * 32 + (lane >> 4) * 8];
        }
#pragma unroll
        for (int m = 0; m < 4; ++m)
#pragma unroll
            for (int nn = 0; nn < 4; ++nn)
                acc[m][nn] = __builtin_amdgcn_mfma_f32_16x16x32_bf16(
                    af[m], bfr[nn], acc[m][nn], 0, 0, 0);
        __syncthreads();
    }

    const float ap = PRELU ? *prelu_a : 0.f;
#pragma unroll
    for (int m = 0; m < 4; ++m) {
        int gr_base = row0 + wr * 64 + m * 16 + (lane >> 4) * 4;
#pragma unroll
        for (int nn = 0; nn < 4; ++nn) {
            int gc = col0 + wc * 64 + nn * 16 + (lane & 15);
            float bv = bias[gc];
#pragma unroll
            for (int j = 0; j < 4; ++j) {
                int gr = gr_base + j;
                if (gr < n) {
                    float v = acc[m][nn][j] + bv;
                    if (PRELU) v = (v >= 0.f) ? v : ap * v;
                    if (OUT_BF16) ((bf16*)outv)[(size_t)gr * HID + gc] = (bf16)v;
                    else         ((float*)outv)[(size_t)gr * HID + gc] = v;
                }
            }
        }
    }
}

extern "C" void kernel_launch(void* const* d_in, const int* in_sizes, int n_in,
                              void* d_out, int out_size, void* d_ws, size_t ws_size,
                              hipStream_t stream) {
    const float* x  = (const float*)d_in[0];
    const void*  ei = d_in[1];
    const float* ew = (const float*)d_in[2];
    const float* W1 = (const float*)d_in[3];
    const float* b1 = (const float*)d_in[4];
    const float* W2 = (const float*)d_in[5];
    const float* b2 = (const float*)d_in[6];
    const float* pa = (const float*)d_in[7];

    char* base = (char*)d_ws;
    bf16*  aggb     = (bf16*)base;                          // 51.2 MB
    bf16*  W1b      = (bf16*)(base + (size_t)N_NODES * HID * 2);
    bf16*  W2b      = W1b + HID * IN_CH;
    float* deg      = (float*)(W2b + HID * HID);
    float* dis      = deg + N_NODES;
    int*   flag     = (int*)(dis + N_NODES);
    int*   counts   = flag + 1;
    int*   cursor   = counts + N_NODES;
    int*   row_ptr  = cursor + N_NODES;                     // N_NODES+1
    int*   srcs     = row_ptr + N_NODES + 1;                // N_EDGES
    float* coefs    = (float*)(srcs + N_EDGES);             // N_EDGES
    int*   partials = (int*)(coefs + N_EDGES);              // SCAN_NBLK

    bf16* p_bf = (bf16*)d_out;   // layer-1 bf16 output lives in d_out, consumed before GEMM2 writes f32

    const int NB = SCAN_NBLK;
    const int EB = (N_EDGES + 255) / 256;

    // ----- CSR build (once, reused by both layers) -----
    init_arrays<<<NB, 256, 0, stream>>>(deg, counts, cursor, flag);
    detect_idx64_par<<<512, 256, 0, stream>>>((const unsigned int*)ei, flag);
    deg_hist<<<EB, 256, 0, stream>>>(ei, ew, deg, counts, flag);
    scan_partial<<<NB, 256, 0, stream>>>(counts, deg, dis, row_ptr, partials);
    scan_partials<<<1, 256, 0, stream>>>(partials, row_ptr);
    scan_add<<<NB, 256, 0, stream>>>(row_ptr, partials);
    fill_csr<<<EB, 256, 0, stream>>>(ei, ew, dis, row_ptr, cursor, srcs, coefs, flag);

    // ----- weight conversion (single launch) -----
    f2b2_kernel<<<(HID * IN_CH + HID * HID + 255) / 256, 256, 0, stream>>>(
        W1, W1b, HID * IN_CH, W2, W2b, HID * HID);

    // ----- layer 1: gather x (f32 in, bf16 out) -> MFMA GEMM + bias + PReLU -> bf16 p -----
    gather_agg_f32<<<(N_NODES + 3) / 4, 256, 0, stream>>>(x, dis, row_ptr, srcs, coefs, aggb);
    gemm_mfma<IN_CH, true, true><<<dim3((N_NODES + 127) / 128, HID / 128), 256, 0, stream>>>(
        aggb, W1b, b1, pa, p_bf, N_NODES);

    // ----- layer 2: gather p (bf16 in/out) -> MFMA GEMM + bias -> f32 d_out -----
    gather_agg_bf16<<<(N_NODES + 3) / 4, 256, 0, stream>>>(p_bf, dis, row_ptr, srcs, coefs, aggb);
    gemm_mfma<HID, false, false><<<dim3((N_NODES + 127) / 128, HID / 128), 256, 0, stream>>>(
        aggb, W2b, b2, pa, (float*)d_out, N_NODES);
}

// Round 6
// 306.647 us; speedup vs baseline: 12.2891x; 1.0008x over previous
//
#include <hip/hip_runtime.h>

#define N_NODES 50000
#define N_EDGES 300000
#define IN_CH 256
#define HID 512
#define SCAN_NBLK ((N_NODES + 255) / 256)   // 196

typedef __bf16 bf16;
typedef bf16 bf16x8 __attribute__((ext_vector_type(8)));
typedef bf16 bf16x4 __attribute__((ext_vector_type(4)));
typedef float f32x4 __attribute__((ext_vector_type(4)));

__device__ __forceinline__ void load_lds16(const void* g, void* l) {
    __builtin_amdgcn_global_load_lds(
        (const __attribute__((address_space(1))) unsigned int*)g,
        (__attribute__((address_space(3))) unsigned int*)l, 16, 0, 0);
}

// ---------- index dtype detection (int32 vs int64), parallel ----------
__global__ void detect_idx64_par(const unsigned int* __restrict__ ei, int* __restrict__ flag) {
    int stride = gridDim.x * blockDim.x;
    int i = blockIdx.x * blockDim.x + threadIdx.x;
    int local = 0;
    for (int idx = 1 + 2 * i; idx < 2 * N_EDGES; idx += 2 * stride)
        local |= (ei[idx] != 0u);
    if (__any(local)) {
        if ((threadIdx.x & 63) == 0) atomicAnd(flag, 0);
    }
}

__device__ __forceinline__ int load_idx(const void* ei, int i, int is64) {
    if (is64) return (int)((const long long*)ei)[i];
    return ((const int*)ei)[i];
}

// ---------- init (deg=1 self-loop, histogram+cursor=0, flag=1) ----------
__global__ void init_arrays(float* __restrict__ deg, int* __restrict__ counts,
                            int* __restrict__ cursor, int* __restrict__ flag) {
    int i = blockIdx.x * blockDim.x + threadIdx.x;
    if (i == 0) *flag = 1;
    if (i < N_NODES) { deg[i] = 1.0f; counts[i] = 0; cursor[i] = 0; }
}

__global__ void deg_hist(const void* __restrict__ ei, const float* __restrict__ ew,
                         float* __restrict__ deg, int* __restrict__ counts,
                         const int* __restrict__ flag) {
    int e = blockIdx.x * blockDim.x + threadIdx.x;
    if (e >= N_EDGES) return;
    int is64 = *flag;
    int d = load_idx(ei, N_EDGES + e, is64);
    atomicAdd(&deg[d], ew[e]);
    atomicAdd(&counts[d], 1);
}

// ---------- parallel scan, phase A: block-local scan + dis (fused) ----------
__global__ __launch_bounds__(256) void scan_partial(
    const int* __restrict__ counts, const float* __restrict__ deg,
    float* __restrict__ dis, int* __restrict__ row_ptr, int* __restrict__ partials)
{
    __shared__ int psum[256];
    int t = threadIdx.x;
    int i = blockIdx.x * 256 + t;
    if (i < N_NODES) {
        float dg = deg[i];
        dis[i] = (dg > 0.f) ? (1.0f / sqrtf(dg)) : 0.f;
    }
    int c = (i < N_NODES) ? counts[i] : 0;
    psum[t] = c;
    __syncthreads();
#pragma unroll
    for (int off = 1; off < 256; off <<= 1) {
        int v = (t >= off) ? psum[t - off] : 0;
        __syncthreads();
        psum[t] += v;
        __syncthreads();
    }
    if (i < N_NODES) row_ptr[i] = psum[t] - c;
    if (t == 255) partials[blockIdx.x] = psum[255];
}

// ---------- phase B: scan the 196 block totals ----------
__global__ __launch_bounds__(256) void scan_partials(int* __restrict__ partials,
                                                     int* __restrict__ row_ptr) {
    __shared__ int psum[256];
    int t = threadIdx.x;
    int p = (t < SCAN_NBLK) ? partials[t] : 0;
    psum[t] = p;
    __syncthreads();
#pragma unroll
    for (int off = 1; off < 256; off <<= 1) {
        int v = (t >= off) ? psum[t - off] : 0;
        __syncthreads();
        psum[t] += v;
        __syncthreads();
    }
    if (t < SCAN_NBLK) partials[t] = psum[t] - p;
    if (t == 255) row_ptr[N_NODES] = psum[255];
}

// ---------- phase C: add block offsets ----------
__global__ void scan_add(int* __restrict__ row_ptr, const int* __restrict__ partials) {
    int i = blockIdx.x * 256 + threadIdx.x;
    if (i < N_NODES) row_ptr[i] += partials[blockIdx.x];
}

__global__ void fill_csr(const void* __restrict__ ei, const float* __restrict__ ew,
                         const float* __restrict__ dis, const int* __restrict__ row_ptr,
                         int* __restrict__ cursor, int* __restrict__ srcs,
                         float* __restrict__ coefs, const int* __restrict__ flag) {
    int e = blockIdx.x * blockDim.x + threadIdx.x;
    if (e >= N_EDGES) return;
    int is64 = *flag;
    int s = load_idx(ei, e, is64);
    int d = load_idx(ei, N_EDGES + e, is64);
    float coef = dis[s] * ew[e] * dis[d];
    int pos = row_ptr[d] + atomicAdd(&cursor[d], 1);
    srcs[pos] = s;
    coefs[pos] = coef;
}

// ---------- f32 -> bf16 convert, both weight matrices in one launch ----------
__global__ void f2b2_kernel(const float* __restrict__ a, bf16* __restrict__ da, int na,
                            const float* __restrict__ b, bf16* __restrict__ db, int nb) {
    int i = blockIdx.x * blockDim.x + threadIdx.x;
    if (i < na) da[i] = (bf16)a[i];
    else if (i - na < nb) db[i - na] = (bf16)b[i - na];
}

// ---------- gather aggregation, f32 input (layer 1), bf16 output ----------
__global__ __launch_bounds__(256) void gather_agg_f32(
    const float* __restrict__ x, const float* __restrict__ dis,
    const int* __restrict__ row_ptr, const int* __restrict__ srcs,
    const float* __restrict__ coefs, bf16* __restrict__ agg)
{
    int wid = threadIdx.x >> 6;
    int lane = threadIdx.x & 63;
    int node = blockIdx.x * 4 + wid;
    if (node >= N_NODES) return;

    float s = dis[node];
    s = s * s;
    float4 t0 = ((const float4*)(x + (size_t)node * IN_CH))[lane];
    float acc0 = s * t0.x, acc1 = s * t0.y, acc2 = s * t0.z, acc3 = s * t0.w;

    int beg = row_ptr[node], end = row_ptr[node + 1];
    for (int j = beg; j < end; ++j) {
        int src = srcs[j];
        float c = coefs[j];
        float4 t = ((const float4*)(x + (size_t)src * IN_CH))[lane];
        acc0 += c * t.x; acc1 += c * t.y; acc2 += c * t.z; acc3 += c * t.w;
    }
    bf16x4 o;
    o[0] = (bf16)acc0; o[1] = (bf16)acc1; o[2] = (bf16)acc2; o[3] = (bf16)acc3;
    *(bf16x4*)(agg + (size_t)node * IN_CH + lane * 4) = o;
}

// ---------- gather aggregation, bf16 input (layer 2), bf16 output ----------
__global__ __launch_bounds__(256) void gather_agg_bf16(
    const bf16* __restrict__ p, const float* __restrict__ dis,
    const int* __restrict__ row_ptr, const int* __restrict__ srcs,
    const float* __restrict__ coefs, bf16* __restrict__ agg)
{
    int wid = threadIdx.x >> 6;
    int lane = threadIdx.x & 63;
    int node = blockIdx.x * 4 + wid;
    if (node >= N_NODES) return;

    float s = dis[node];
    s = s * s;
    float acc[8];
    bf16x8 t0 = *(const bf16x8*)(p + (size_t)node * HID + lane * 8);
#pragma unroll
    for (int i = 0; i < 8; ++i) acc[i] = s * (float)t0[i];

    int beg = row_ptr[node], end = row_ptr[node + 1];
    for (int j = beg; j < end; ++j) {
        int src = srcs[j];
        float c = coefs[j];
        bf16x8 t = *(const bf16x8*)(p + (size_t)src * HID + lane * 8);
#pragma unroll
        for (int i = 0; i < 8; ++i) acc[i] += c * (float)t[i];
    }
    bf16x8 o;
#pragma unroll
    for (int i = 0; i < 8; ++i) o[i] = (bf16)acc[i];
    *(bf16x8*)(agg + (size_t)node * HID + lane * 8) = o;
}

// ---------- MFMA bf16 GEMM: out[n,512] = X[n,K] @ Wt[512,K]^T + bias ----------
// 128x128 tile, BK=64, grid (cols=4, rows), XOR-swizzled LDS (linear gload_lds
// dest + inverse-permuted global source + swizzled ds_read — both-sides rule).
template <int K, bool PRELU, bool OUT_BF16>
__global__ __launch_bounds__(256) void gemm_mfma(
    const bf16* __restrict__ X, const bf16* __restrict__ Wt,
    const float* __restrict__ bias, const float* __restrict__ prelu_a,
    void* __restrict__ outv, int n)
{
    __shared__ __align__(16) bf16 As[128 * 64];
    __shared__ __align__(16) bf16 Bs[128 * 64];
    const int tid = threadIdx.x;
    const int lane = tid & 63;
    const int wid = tid >> 6;
    const int wr = wid >> 1, wc = wid & 1;
    const int row0 = blockIdx.y * 128;      // rows on y (4 col-blocks adjacent in dispatch)
    const int col0 = blockIdx.x * 128;

    f32x4 acc[4][4] = {};

    for (int k0 = 0; k0 < K; k0 += 64) {
        // stage 128x64 of A and B; LDS segment ss holds global 16B-col (ss&7)^(r&7)
#pragma unroll
        for (int h = 0; h < 4; ++h) {
            int ss = tid + h * 256;          // 0..1023
            int r = ss >> 3;                 // 0..127
            int c = (ss & 7) ^ (r & 7);      // inverse-permuted source col
            int ra = row0 + r; if (ra >= n) ra = n - 1;
            load_lds16(X + (size_t)ra * K + k0 + c * 8, &As[ss * 8]);
            load_lds16(Wt + (size_t)(col0 + r) * K + k0 + c * 8, &Bs[ss * 8]);
        }
        __syncthreads();

#pragma unroll
        for (int kk = 0; kk < 2; ++kk) {
            bf16x8 af[4], bfr[4];
#pragma unroll
            for (int m = 0; m < 4; ++m) {
                int r = wr * 64 + m * 16 + (lane & 15);
                int c = kk * 4 + (lane >> 4);
                af[m] = *(const bf16x8*)&As[(r * 8 + (c ^ (r & 7))) * 8];
            }
#pragma unroll
            for (int nn = 0; nn < 4; ++nn) {
                int r = wc * 64 + nn * 16 + (lane & 15);
                int c = kk * 4 + (lane >> 4);
                bfr[nn] = *(const bf16x8*)&Bs[(r * 8 + (c ^ (r & 7))) * 8];
            }
#pragma unroll
            for (int m = 0; m < 4; ++m)
#pragma unroll
                for (int nn = 0; nn < 4; ++nn)
                    acc[m][nn] = __builtin_amdgcn_mfma_f32_16x16x32_bf16(
                        af[m], bfr[nn], acc[m][nn], 0, 0, 0);
        }
        __syncthreads();
    }

    const float ap = PRELU ? *prelu_a : 0.f;
#pragma unroll
    for (int m = 0; m < 4; ++m) {
        int gr_base = row0 + wr * 64 + m * 16 + (lane >> 4) * 4;
#pragma unroll
        for (int nn = 0; nn < 4; ++nn) {
            int gc = col0 + wc * 64 + nn * 16 + (lane & 15);
            float bv = bias[gc];
#pragma unroll
            for (int j = 0; j < 4; ++j) {
                int gr = gr_base + j;
                if (gr < n) {
                    float v = acc[m][nn][j] + bv;
                    if (PRELU) v = (v >= 0.f) ? v : ap * v;
                    if (OUT_BF16) ((bf16*)outv)[(size_t)gr * HID + gc] = (bf16)v;
                    else         ((float*)outv)[(size_t)gr * HID + gc] = v;
                }
            }
        }
    }
}

extern "C" void kernel_launch(void* const* d_in, const int* in_sizes, int n_in,
                              void* d_out, int out_size, void* d_ws, size_t ws_size,
                              hipStream_t stream) {
    const float* x  = (const float*)d_in[0];
    const void*  ei = d_in[1];
    const float* ew = (const float*)d_in[2];
    const float* W1 = (const float*)d_in[3];
    const float* b1 = (const float*)d_in[4];
    const float* W2 = (const float*)d_in[5];
    const float* b2 = (const float*)d_in[6];
    const float* pa = (const float*)d_in[7];

    char* base = (char*)d_ws;
    bf16*  aggb     = (bf16*)base;                          // 51.2 MB
    bf16*  W1b      = (bf16*)(base + (size_t)N_NODES * HID * 2);
    bf16*  W2b      = W1b + HID * IN_CH;
    float* deg      = (float*)(W2b + HID * HID);
    float* dis      = deg + N_NODES;
    int*   flag     = (int*)(dis + N_NODES);
    int*   counts   = flag + 1;
    int*   cursor   = counts + N_NODES;
    int*   row_ptr  = cursor + N_NODES;                     // N_NODES+1
    int*   srcs     = row_ptr + N_NODES + 1;                // N_EDGES
    float* coefs    = (float*)(srcs + N_EDGES);             // N_EDGES
    int*   partials = (int*)(coefs + N_EDGES);              // SCAN_NBLK

    bf16* p_bf = (bf16*)d_out;   // layer-1 bf16 output lives in d_out, consumed before GEMM2 writes f32

    const int NB = SCAN_NBLK;
    const int EB = (N_EDGES + 255) / 256;

    // ----- CSR build (once, reused by both layers) -----
    init_arrays<<<NB, 256, 0, stream>>>(deg, counts, cursor, flag);
    detect_idx64_par<<<512, 256, 0, stream>>>((const unsigned int*)ei, flag);
    deg_hist<<<EB, 256, 0, stream>>>(ei, ew, deg, counts, flag);
    scan_partial<<<NB, 256, 0, stream>>>(counts, deg, dis, row_ptr, partials);
    scan_partials<<<1, 256, 0, stream>>>(partials, row_ptr);
    scan_add<<<NB, 256, 0, stream>>>(row_ptr, partials);
    fill_csr<<<EB, 256, 0, stream>>>(ei, ew, dis, row_ptr, cursor, srcs, coefs, flag);

    // ----- weight conversion (single launch) -----
    f2b2_kernel<<<(HID * IN_CH + HID * HID + 255) / 256, 256, 0, stream>>>(
        W1, W1b, HID * IN_CH, W2, W2b, HID * HID);

    // ----- layer 1: gather x (f32 in, bf16 out) -> MFMA GEMM + bias + PReLU -> bf16 p -----
    gather_agg_f32<<<(N_NODES + 3) / 4, 256, 0, stream>>>(x, dis, row_ptr, srcs, coefs, aggb);
    gemm_mfma<IN_CH, true, true><<<dim3(HID / 128, (N_NODES + 127) / 128), 256, 0, stream>>>(
        aggb, W1b, b1, pa, p_bf, N_NODES);

    // ----- layer 2: gather p (bf16 in/out) -> MFMA GEMM + bias -> f32 d_out -----
    gather_agg_bf16<<<(N_NODES + 3) / 4, 256, 0, stream>>>(p_bf, dis, row_ptr, srcs, coefs, aggb);
    gemm_mfma<HID, false, false><<<dim3(HID / 128, (N_NODES + 127) / 128), 256, 0, stream>>>(
        aggb, W2b, b2, pa, (float*)d_out, N_NODES);
}

// Round 7
// 290.662 us; speedup vs baseline: 12.9650x; 1.0550x over previous
//
#include <hip/hip_runtime.h>

#define N_NODES 50000
#define N_EDGES 300000
#define IN_CH 256
#define HID 512
#define SCAN_NBLK ((N_NODES + 255) / 256)   // 196

typedef __bf16 bf16;
typedef bf16 bf16x8 __attribute__((ext_vector_type(8)));
typedef bf16 bf16x4 __attribute__((ext_vector_type(4)));
typedef float f32x4 __attribute__((ext_vector_type(4)));

__device__ __forceinline__ void load_lds16(const void* g, void* l) {
    __builtin_amdgcn_global_load_lds(
        (const __attribute__((address_space(1))) unsigned int*)g,
        (__attribute__((address_space(3))) unsigned int*)l, 16, 0, 0);
}

// ---------- index dtype detection (int32 vs int64), parallel ----------
__global__ void detect_idx64_par(const unsigned int* __restrict__ ei, int* __restrict__ flag) {
    int stride = gridDim.x * blockDim.x;
    int i = blockIdx.x * blockDim.x + threadIdx.x;
    int local = 0;
    for (int idx = 1 + 2 * i; idx < 2 * N_EDGES; idx += 2 * stride)
        local |= (ei[idx] != 0u);
    if (__any(local)) {
        if ((threadIdx.x & 63) == 0) atomicAnd(flag, 0);
    }
}

__device__ __forceinline__ int load_idx(const void* ei, int i, int is64) {
    if (is64) return (int)((const long long*)ei)[i];
    return ((const int*)ei)[i];
}

// ---------- init (deg=1 self-loop, histogram+cursor=0, flag=1) ----------
__global__ void init_arrays(float* __restrict__ deg, int* __restrict__ counts,
                            int* __restrict__ cursor, int* __restrict__ flag) {
    int i = blockIdx.x * blockDim.x + threadIdx.x;
    if (i == 0) *flag = 1;
    if (i < N_NODES) { deg[i] = 1.0f; counts[i] = 0; cursor[i] = 0; }
}

__global__ void deg_hist(const void* __restrict__ ei, const float* __restrict__ ew,
                         float* __restrict__ deg, int* __restrict__ counts,
                         const int* __restrict__ flag) {
    int e = blockIdx.x * blockDim.x + threadIdx.x;
    if (e >= N_EDGES) return;
    int is64 = *flag;
    int d = load_idx(ei, N_EDGES + e, is64);
    atomicAdd(&deg[d], ew[e]);
    atomicAdd(&counts[d], 1);
}

// ---------- parallel scan, phase A: block-local scan + dis (fused) ----------
__global__ __launch_bounds__(256) void scan_partial(
    const int* __restrict__ counts, const float* __restrict__ deg,
    float* __restrict__ dis, int* __restrict__ row_ptr, int* __restrict__ partials)
{
    __shared__ int psum[256];
    int t = threadIdx.x;
    int i = blockIdx.x * 256 + t;
    if (i < N_NODES) {
        float dg = deg[i];
        dis[i] = (dg > 0.f) ? (1.0f / sqrtf(dg)) : 0.f;
    }
    int c = (i < N_NODES) ? counts[i] : 0;
    psum[t] = c;
    __syncthreads();
#pragma unroll
    for (int off = 1; off < 256; off <<= 1) {
        int v = (t >= off) ? psum[t - off] : 0;
        __syncthreads();
        psum[t] += v;
        __syncthreads();
    }
    if (i < N_NODES) row_ptr[i] = psum[t] - c;
    if (t == 255) partials[blockIdx.x] = psum[255];
}

// ---------- phase B: scan the 196 block totals ----------
__global__ __launch_bounds__(256) void scan_partials(int* __restrict__ partials,
                                                     int* __restrict__ row_ptr) {
    __shared__ int psum[256];
    int t = threadIdx.x;
    int p = (t < SCAN_NBLK) ? partials[t] : 0;
    psum[t] = p;
    __syncthreads();
#pragma unroll
    for (int off = 1; off < 256; off <<= 1) {
        int v = (t >= off) ? psum[t - off] : 0;
        __syncthreads();
        psum[t] += v;
        __syncthreads();
    }
    if (t < SCAN_NBLK) partials[t] = psum[t] - p;
    if (t == 255) row_ptr[N_NODES] = psum[255];
}

// ---------- phase C: add block offsets ----------
__global__ void scan_add(int* __restrict__ row_ptr, const int* __restrict__ partials) {
    int i = blockIdx.x * 256 + threadIdx.x;
    if (i < N_NODES) row_ptr[i] += partials[blockIdx.x];
}

__global__ void fill_csr(const void* __restrict__ ei, const float* __restrict__ ew,
                         const float* __restrict__ dis, const int* __restrict__ row_ptr,
                         int* __restrict__ cursor, int* __restrict__ srcs,
                         float* __restrict__ coefs, const int* __restrict__ flag) {
    int e = blockIdx.x * blockDim.x + threadIdx.x;
    if (e >= N_EDGES) return;
    int is64 = *flag;
    int s = load_idx(ei, e, is64);
    int d = load_idx(ei, N_EDGES + e, is64);
    float coef = dis[s] * ew[e] * dis[d];
    int pos = row_ptr[d] + atomicAdd(&cursor[d], 1);
    srcs[pos] = s;
    coefs[pos] = coef;
}

// ---------- f32 -> bf16: weights (scalar, small) ----------
__global__ void f2b2_kernel(const float* __restrict__ a, bf16* __restrict__ da, int na,
                            const float* __restrict__ b, bf16* __restrict__ db, int nb) {
    int i = blockIdx.x * blockDim.x + threadIdx.x;
    if (i < na) da[i] = (bf16)a[i];
    else if (i - na < nb) db[i - na] = (bf16)b[i - na];
}

// ---------- f32 -> bf16: x feature matrix (vectorized, 8 elems/thread) ----------
__global__ void f2bx_kernel(const float* __restrict__ s, bf16* __restrict__ d) {
    int i = blockIdx.x * blockDim.x + threadIdx.x;    // one per 8 elements
    const int total = N_NODES * IN_CH / 8;
    if (i >= total) return;
    float4 a = ((const float4*)s)[i * 2];
    float4 b = ((const float4*)s)[i * 2 + 1];
    bf16x8 o;
    o[0] = (bf16)a.x; o[1] = (bf16)a.y; o[2] = (bf16)a.z; o[3] = (bf16)a.w;
    o[4] = (bf16)b.x; o[5] = (bf16)b.y; o[6] = (bf16)b.z; o[7] = (bf16)b.w;
    *(bf16x8*)(d + (size_t)i * 8) = o;
}

// ---------- gather aggregation, bf16 rows, C=256 (layer 1) ----------
__global__ __launch_bounds__(256) void gather_agg_c256(
    const bf16* __restrict__ xb, const float* __restrict__ dis,
    const int* __restrict__ row_ptr, const int* __restrict__ srcs,
    const float* __restrict__ coefs, bf16* __restrict__ agg)
{
    int wid = threadIdx.x >> 6;
    int lane = threadIdx.x & 63;
    int node = blockIdx.x * 4 + wid;
    if (node >= N_NODES) return;

    float s = dis[node];
    s = s * s;
    float acc[4];
    bf16x4 t0 = *(const bf16x4*)(xb + (size_t)node * IN_CH + lane * 4);
#pragma unroll
    for (int i = 0; i < 4; ++i) acc[i] = s * (float)t0[i];

    int beg = row_ptr[node], end = row_ptr[node + 1];
    int j = beg;
    for (; j + 2 <= end; j += 2) {
        int s0 = srcs[j], s1 = srcs[j + 1];
        float c0 = coefs[j], c1 = coefs[j + 1];
        bf16x4 r0 = *(const bf16x4*)(xb + (size_t)s0 * IN_CH + lane * 4);
        bf16x4 r1 = *(const bf16x4*)(xb + (size_t)s1 * IN_CH + lane * 4);
#pragma unroll
        for (int i = 0; i < 4; ++i) acc[i] += c0 * (float)r0[i];
#pragma unroll
        for (int i = 0; i < 4; ++i) acc[i] += c1 * (float)r1[i];
    }
    if (j < end) {
        int s0 = srcs[j];
        float c0 = coefs[j];
        bf16x4 r0 = *(const bf16x4*)(xb + (size_t)s0 * IN_CH + lane * 4);
#pragma unroll
        for (int i = 0; i < 4; ++i) acc[i] += c0 * (float)r0[i];
    }
    bf16x4 o;
#pragma unroll
    for (int i = 0; i < 4; ++i) o[i] = (bf16)acc[i];
    *(bf16x4*)(agg + (size_t)node * IN_CH + lane * 4) = o;
}

// ---------- gather aggregation, bf16 rows, C=512 (layer 2) ----------
__global__ __launch_bounds__(256) void gather_agg_c512(
    const bf16* __restrict__ p, const float* __restrict__ dis,
    const int* __restrict__ row_ptr, const int* __restrict__ srcs,
    const float* __restrict__ coefs, bf16* __restrict__ agg)
{
    int wid = threadIdx.x >> 6;
    int lane = threadIdx.x & 63;
    int node = blockIdx.x * 4 + wid;
    if (node >= N_NODES) return;

    float s = dis[node];
    s = s * s;
    float acc[8];
    bf16x8 t0 = *(const bf16x8*)(p + (size_t)node * HID + lane * 8);
#pragma unroll
    for (int i = 0; i < 8; ++i) acc[i] = s * (float)t0[i];

    int beg = row_ptr[node], end = row_ptr[node + 1];
    int j = beg;
    for (; j + 2 <= end; j += 2) {
        int s0 = srcs[j], s1 = srcs[j + 1];
        float c0 = coefs[j], c1 = coefs[j + 1];
        bf16x8 r0 = *(const bf16x8*)(p + (size_t)s0 * HID + lane * 8);
        bf16x8 r1 = *(const bf16x8*)(p + (size_t)s1 * HID + lane * 8);
#pragma unroll
        for (int i = 0; i < 8; ++i) acc[i] += c0 * (float)r0[i];
#pragma unroll
        for (int i = 0; i < 8; ++i) acc[i] += c1 * (float)r1[i];
    }
    if (j < end) {
        int s0 = srcs[j];
        float c0 = coefs[j];
        bf16x8 r0 = *(const bf16x8*)(p + (size_t)s0 * HID + lane * 8);
#pragma unroll
        for (int i = 0; i < 8; ++i) acc[i] += c0 * (float)r0[i];
    }
    bf16x8 o;
#pragma unroll
    for (int i = 0; i < 8; ++i) o[i] = (bf16)acc[i];
    *(bf16x8*)(agg + (size_t)node * HID + lane * 8) = o;
}

// ---------- MFMA bf16 GEMM: out[n,512] = X[n,K] @ Wt[512,K]^T + bias ----------
// 128x128 tile, BK=32 (R5 structure: best occupancy), cols-fast grid,
// light seg-swizzle c^(r&3): 8-way conflict -> free 2-way.
template <int K, bool PRELU, bool OUT_BF16>
__global__ __launch_bounds__(256) void gemm_mfma(
    const bf16* __restrict__ X, const bf16* __restrict__ Wt,
    const float* __restrict__ bias, const float* __restrict__ prelu_a,
    void* __restrict__ outv, int n)
{
    __shared__ __align__(16) bf16 As[128 * 32];
    __shared__ __align__(16) bf16 Bs[128 * 32];
    const int tid = threadIdx.x;
    const int lane = tid & 63;
    const int wid = tid >> 6;
    const int wr = wid >> 1, wc = wid & 1;
    const int row0 = blockIdx.y * 128;      // cols on x: 4 col-blocks dispatch-adjacent
    const int col0 = blockIdx.x * 128;

    f32x4 acc[4][4] = {};

    for (int k0 = 0; k0 < K; k0 += 32) {
#pragma unroll
        for (int h = 0; h < 2; ++h) {
            int ss = tid + h * 256;          // 0..511
            int r = ss >> 2;                 // 0..127
            int c = (ss & 3) ^ (r & 3);      // inverse-permuted source seg
            int ra = row0 + r; if (ra >= n) ra = n - 1;
            load_lds16(X + (size_t)ra * K + k0 + c * 8, &As[ss * 8]);
            load_lds16(Wt + (size_t)(col0 + r) * K + k0 + c * 8, &Bs[ss * 8]);
        }
        __syncthreads();

        bf16x8 af[4], bfr[4];
#pragma unroll
        for (int m = 0; m < 4; ++m) {
            int r = wr * 64 + m * 16 + (lane & 15);
            int seg = r * 4 + ((lane >> 4) ^ (r & 3));
            af[m] = *(const bf16x8*)&As[seg * 8];
        }
#pragma unroll
        for (int nn = 0; nn < 4; ++nn) {
            int r = wc * 64 + nn * 16 + (lane & 15);
            int seg = r * 4 + ((lane >> 4) ^ (r & 3));
            bfr[nn] = *(const bf16x8*)&Bs[seg * 8];
        }
#pragma unroll
        for (int m = 0; m < 4; ++m)
#pragma unroll
            for (int nn = 0; nn < 4; ++nn)
                acc[m][nn] = __builtin_amdgcn_mfma_f32_16x16x32_bf16(
                    af[m], bfr[nn], acc[m][nn], 0, 0, 0);
        __syncthreads();
    }

    const float ap = PRELU ? *prelu_a : 0.f;
#pragma unroll
    for (int m = 0; m < 4; ++m) {
        int gr_base = row0 + wr * 64 + m * 16 + (lane >> 4) * 4;
#pragma unroll
        for (int nn = 0; nn < 4; ++nn) {
            int gc = col0 + wc * 64 + nn * 16 + (lane & 15);
            float bv = bias[gc];
#pragma unroll
            for (int j = 0; j < 4; ++j) {
                int gr = gr_base + j;
                if (gr < n) {
                    float v = acc[m][nn][j] + bv;
                    if (PRELU) v = (v >= 0.f) ? v : ap * v;
                    if (OUT_BF16) ((bf16*)outv)[(size_t)gr * HID + gc] = (bf16)v;
                    else         ((float*)outv)[(size_t)gr * HID + gc] = v;
                }
            }
        }
    }
}

extern "C" void kernel_launch(void* const* d_in, const int* in_sizes, int n_in,
                              void* d_out, int out_size, void* d_ws, size_t ws_size,
                              hipStream_t stream) {
    const float* x  = (const float*)d_in[0];
    const void*  ei = d_in[1];
    const float* ew = (const float*)d_in[2];
    const float* W1 = (const float*)d_in[3];
    const float* b1 = (const float*)d_in[4];
    const float* W2 = (const float*)d_in[5];
    const float* b2 = (const float*)d_in[6];
    const float* pa = (const float*)d_in[7];

    char* base = (char*)d_ws;
    bf16*  aggb     = (bf16*)base;                          // 51.2 MB
    bf16*  xb       = (bf16*)(base + (size_t)N_NODES * HID * 2);   // 25.6 MB
    bf16*  W1b      = xb + (size_t)N_NODES * IN_CH;
    bf16*  W2b      = W1b + HID * IN_CH;
    float* deg      = (float*)(W2b + HID * HID);
    float* dis      = deg + N_NODES;
    int*   flag     = (int*)(dis + N_NODES);
    int*   counts   = flag + 1;
    int*   cursor   = counts + N_NODES;
    int*   row_ptr  = cursor + N_NODES;                     // N_NODES+1
    int*   srcs     = row_ptr + N_NODES + 1;                // N_EDGES
    float* coefs    = (float*)(srcs + N_EDGES);             // N_EDGES
    int*   partials = (int*)(coefs + N_EDGES);              // SCAN_NBLK

    bf16* p_bf = (bf16*)d_out;   // layer-1 bf16 output lives in d_out, consumed before GEMM2 writes f32

    const int NB = SCAN_NBLK;
    const int EB = (N_EDGES + 255) / 256;

    // ----- CSR build (once, reused by both layers) -----
    init_arrays<<<NB, 256, 0, stream>>>(deg, counts, cursor, flag);
    detect_idx64_par<<<512, 256, 0, stream>>>((const unsigned int*)ei, flag);
    deg_hist<<<EB, 256, 0, stream>>>(ei, ew, deg, counts, flag);
    scan_partial<<<NB, 256, 0, stream>>>(counts, deg, dis, row_ptr, partials);
    scan_partials<<<1, 256, 0, stream>>>(partials, row_ptr);
    scan_add<<<NB, 256, 0, stream>>>(row_ptr, partials);
    fill_csr<<<EB, 256, 0, stream>>>(ei, ew, dis, row_ptr, cursor, srcs, coefs, flag);

    // ----- dtype conversions (weights scalar; x vectorized) -----
    f2b2_kernel<<<(HID * IN_CH + HID * HID + 255) / 256, 256, 0, stream>>>(
        W1, W1b, HID * IN_CH, W2, W2b, HID * HID);
    f2bx_kernel<<<(N_NODES * IN_CH / 8 + 255) / 256, 256, 0, stream>>>(x, xb);

    // ----- layer 1: gather bf16 x -> MFMA GEMM + bias + PReLU -> bf16 p (in d_out) -----
    gather_agg_c256<<<(N_NODES + 3) / 4, 256, 0, stream>>>(xb, dis, row_ptr, srcs, coefs, aggb);
    gemm_mfma<IN_CH, true, true><<<dim3(HID / 128, (N_NODES + 127) / 128), 256, 0, stream>>>(
        aggb, W1b, b1, pa, p_bf, N_NODES);

    // ----- layer 2: gather bf16 p -> MFMA GEMM + bias -> f32 d_out -----
    gather_agg_c512<<<(N_NODES + 3) / 4, 256, 0, stream>>>(p_bf, dis, row_ptr, srcs, coefs, aggb);
    gemm_mfma<HID, false, false><<<dim3(HID / 128, (N_NODES + 127) / 128), 256, 0, stream>>>(
        aggb, W2b, b2, pa, (float*)d_out, N_NODES);
}

// Round 8
// 280.234 us; speedup vs baseline: 13.4474x; 1.0372x over previous
//
#include <hip/hip_runtime.h>

#define N_NODES 50000
#define N_EDGES 300000
#define IN_CH 256
#define HID 512
#define SCAN_NBLK ((N_NODES + 255) / 256)   // 196

typedef __bf16 bf16;
typedef bf16 bf16x8 __attribute__((ext_vector_type(8)));
typedef bf16 bf16x4 __attribute__((ext_vector_type(4)));
typedef float f32x4 __attribute__((ext_vector_type(4)));

__device__ __forceinline__ void load_lds16(const void* g, void* l) {
    __builtin_amdgcn_global_load_lds(
        (const __attribute__((address_space(1))) unsigned int*)g,
        (__attribute__((address_space(3))) unsigned int*)l, 16, 0, 0);
}

// ---------- index dtype detection (int32 vs int64), parallel ----------
__global__ void detect_idx64_par(const unsigned int* __restrict__ ei, int* __restrict__ flag) {
    int stride = gridDim.x * blockDim.x;
    int i = blockIdx.x * blockDim.x + threadIdx.x;
    int local = 0;
    for (int idx = 1 + 2 * i; idx < 2 * N_EDGES; idx += 2 * stride)
        local |= (ei[idx] != 0u);
    if (__any(local)) {
        if ((threadIdx.x & 63) == 0) atomicAnd(flag, 0);
    }
}

__device__ __forceinline__ int load_idx(const void* ei, int i, int is64) {
    if (is64) return (int)((const long long*)ei)[i];
    return ((const int*)ei)[i];
}

// ---------- init (deg=1 self-loop, histogram+cursor=0, flag=1) ----------
__global__ void init_arrays(float* __restrict__ deg, int* __restrict__ counts,
                            int* __restrict__ cursor, int* __restrict__ flag) {
    int i = blockIdx.x * blockDim.x + threadIdx.x;
    if (i == 0) *flag = 1;
    if (i < N_NODES) { deg[i] = 1.0f; counts[i] = 0; cursor[i] = 0; }
}

__global__ void deg_hist(const void* __restrict__ ei, const float* __restrict__ ew,
                         float* __restrict__ deg, int* __restrict__ counts,
                         const int* __restrict__ flag) {
    int e = blockIdx.x * blockDim.x + threadIdx.x;
    if (e >= N_EDGES) return;
    int is64 = *flag;
    int d = load_idx(ei, N_EDGES + e, is64);
    atomicAdd(&deg[d], ew[e]);
    atomicAdd(&counts[d], 1);
}

// ---------- parallel scan, phase A: block-local scan + dis (fused) ----------
__global__ __launch_bounds__(256) void scan_partial(
    const int* __restrict__ counts, const float* __restrict__ deg,
    float* __restrict__ dis, int* __restrict__ row_ptr, int* __restrict__ partials)
{
    __shared__ int psum[256];
    int t = threadIdx.x;
    int i = blockIdx.x * 256 + t;
    if (i < N_NODES) {
        float dg = deg[i];
        dis[i] = (dg > 0.f) ? (1.0f / sqrtf(dg)) : 0.f;
    }
    int c = (i < N_NODES) ? counts[i] : 0;
    psum[t] = c;
    __syncthreads();
#pragma unroll
    for (int off = 1; off < 256; off <<= 1) {
        int v = (t >= off) ? psum[t - off] : 0;
        __syncthreads();
        psum[t] += v;
        __syncthreads();
    }
    if (i < N_NODES) row_ptr[i] = psum[t] - c;
    if (t == 255) partials[blockIdx.x] = psum[255];
}

// ---------- phase B: scan the 196 block totals ----------
__global__ __launch_bounds__(256) void scan_partials(int* __restrict__ partials,
                                                     int* __restrict__ row_ptr) {
    __shared__ int psum[256];
    int t = threadIdx.x;
    int p = (t < SCAN_NBLK) ? partials[t] : 0;
    psum[t] = p;
    __syncthreads();
#pragma unroll
    for (int off = 1; off < 256; off <<= 1) {
        int v = (t >= off) ? psum[t - off] : 0;
        __syncthreads();
        psum[t] += v;
        __syncthreads();
    }
    if (t < SCAN_NBLK) partials[t] = psum[t] - p;
    if (t == 255) row_ptr[N_NODES] = psum[255];
}

// ---------- phase C: add block offsets ----------
__global__ void scan_add(int* __restrict__ row_ptr, const int* __restrict__ partials) {
    int i = blockIdx.x * 256 + threadIdx.x;
    if (i < N_NODES) row_ptr[i] += partials[blockIdx.x];
}

__global__ void fill_csr(const void* __restrict__ ei, const float* __restrict__ ew,
                         const float* __restrict__ dis, const int* __restrict__ row_ptr,
                         int* __restrict__ cursor, int* __restrict__ srcs,
                         float* __restrict__ coefs, const int* __restrict__ flag) {
    int e = blockIdx.x * blockDim.x + threadIdx.x;
    if (e >= N_EDGES) return;
    int is64 = *flag;
    int s = load_idx(ei, e, is64);
    int d = load_idx(ei, N_EDGES + e, is64);
    float coef = dis[s] * ew[e] * dis[d];
    int pos = row_ptr[d] + atomicAdd(&cursor[d], 1);
    srcs[pos] = s;
    coefs[pos] = coef;
}

// ---------- f32 -> bf16: weights (scalar, small) ----------
__global__ void f2b2_kernel(const float* __restrict__ a, bf16* __restrict__ da, int na,
                            const float* __restrict__ b, bf16* __restrict__ db, int nb) {
    int i = blockIdx.x * blockDim.x + threadIdx.x;
    if (i < na) da[i] = (bf16)a[i];
    else if (i - na < nb) db[i - na] = (bf16)b[i - na];
}

// ---------- f32 -> bf16: x feature matrix (vectorized, 8 elems/thread) ----------
__global__ void f2bx_kernel(const float* __restrict__ s, bf16* __restrict__ d) {
    int i = blockIdx.x * blockDim.x + threadIdx.x;    // one per 8 elements
    const int total = N_NODES * IN_CH / 8;
    if (i >= total) return;
    float4 a = ((const float4*)s)[i * 2];
    float4 b = ((const float4*)s)[i * 2 + 1];
    bf16x8 o;
    o[0] = (bf16)a.x; o[1] = (bf16)a.y; o[2] = (bf16)a.z; o[3] = (bf16)a.w;
    o[4] = (bf16)b.x; o[5] = (bf16)b.y; o[6] = (bf16)b.z; o[7] = (bf16)b.w;
    *(bf16x8*)(d + (size_t)i * 8) = o;
}

// ---------- gather aggregation, bf16 rows, C=256 (layer 1) ----------
__global__ __launch_bounds__(256) void gather_agg_c256(
    const bf16* __restrict__ xb, const float* __restrict__ dis,
    const int* __restrict__ row_ptr, const int* __restrict__ srcs,
    const float* __restrict__ coefs, bf16* __restrict__ agg)
{
    int wid = threadIdx.x >> 6;
    int lane = threadIdx.x & 63;
    int node = blockIdx.x * 4 + wid;
    if (node >= N_NODES) return;

    float s = dis[node];
    s = s * s;
    float acc[4];
    bf16x4 t0 = *(const bf16x4*)(xb + (size_t)node * IN_CH + lane * 4);
#pragma unroll
    for (int i = 0; i < 4; ++i) acc[i] = s * (float)t0[i];

    int beg = row_ptr[node], end = row_ptr[node + 1];
    int j = beg;
    for (; j + 2 <= end; j += 2) {
        int s0 = srcs[j], s1 = srcs[j + 1];
        float c0 = coefs[j], c1 = coefs[j + 1];
        bf16x4 r0 = *(const bf16x4*)(xb + (size_t)s0 * IN_CH + lane * 4);
        bf16x4 r1 = *(const bf16x4*)(xb + (size_t)s1 * IN_CH + lane * 4);
#pragma unroll
        for (int i = 0; i < 4; ++i) acc[i] += c0 * (float)r0[i];
#pragma unroll
        for (int i = 0; i < 4; ++i) acc[i] += c1 * (float)r1[i];
    }
    if (j < end) {
        int s0 = srcs[j];
        float c0 = coefs[j];
        bf16x4 r0 = *(const bf16x4*)(xb + (size_t)s0 * IN_CH + lane * 4);
#pragma unroll
        for (int i = 0; i < 4; ++i) acc[i] += c0 * (float)r0[i];
    }
    bf16x4 o;
#pragma unroll
    for (int i = 0; i < 4; ++i) o[i] = (bf16)acc[i];
    *(bf16x4*)(agg + (size_t)node * IN_CH + lane * 4) = o;
}

// ---------- gather aggregation, bf16 rows, C=512 (layer 2) ----------
__global__ __launch_bounds__(256) void gather_agg_c512(
    const bf16* __restrict__ p, const float* __restrict__ dis,
    const int* __restrict__ row_ptr, const int* __restrict__ srcs,
    const float* __restrict__ coefs, bf16* __restrict__ agg)
{
    int wid = threadIdx.x >> 6;
    int lane = threadIdx.x & 63;
    int node = blockIdx.x * 4 + wid;
    if (node >= N_NODES) return;

    float s = dis[node];
    s = s * s;
    float acc[8];
    bf16x8 t0 = *(const bf16x8*)(p + (size_t)node * HID + lane * 8);
#pragma unroll
    for (int i = 0; i < 8; ++i) acc[i] = s * (float)t0[i];

    int beg = row_ptr[node], end = row_ptr[node + 1];
    int j = beg;
    for (; j + 2 <= end; j += 2) {
        int s0 = srcs[j], s1 = srcs[j + 1];
        float c0 = coefs[j], c1 = coefs[j + 1];
        bf16x8 r0 = *(const bf16x8*)(p + (size_t)s0 * HID + lane * 8);
        bf16x8 r1 = *(const bf16x8*)(p + (size_t)s1 * HID + lane * 8);
#pragma unroll
        for (int i = 0; i < 8; ++i) acc[i] += c0 * (float)r0[i];
#pragma unroll
        for (int i = 0; i < 8; ++i) acc[i] += c1 * (float)r1[i];
    }
    if (j < end) {
        int s0 = srcs[j];
        float c0 = coefs[j];
        bf16x8 r0 = *(const bf16x8*)(p + (size_t)s0 * HID + lane * 8);
#pragma unroll
        for (int i = 0; i < 8; ++i) acc[i] += c0 * (float)r0[i];
    }
    bf16x8 o;
#pragma unroll
    for (int i = 0; i < 8; ++i) o[i] = (bf16)acc[i];
    *(bf16x8*)(agg + (size_t)node * HID + lane * 8) = o;
}

// ---------- MFMA bf16 GEMM: out[n,512] = X[n,K] @ Wt[512,K]^T + bias ----------
// 128x128 tile, BK=32, 1D grid with bijective chunked XCD swizzle (m204):
// each XCD gets a contiguous col-fast chunk -> the 4 col-blocks of a row
// tile share that XCD's L2 -> A-panel HBM-fetched once.
template <int K, bool PRELU, bool OUT_BF16>
__global__ __launch_bounds__(256) void gemm_mfma(
    const bf16* __restrict__ X, const bf16* __restrict__ Wt,
    const float* __restrict__ bias, const float* __restrict__ prelu_a,
    void* __restrict__ outv, int n)
{
    __shared__ __align__(16) bf16 As[128 * 32];
    __shared__ __align__(16) bf16 Bs[128 * 32];
    const int tid = threadIdx.x;
    const int lane = tid & 63;
    const int wid = tid >> 6;
    const int wr = wid >> 1, wc = wid & 1;

    // bijective chunked XCD swizzle (nwg % 8 may be != 0)
    const int nwg = gridDim.x;
    const int q = nwg >> 3, r8 = nwg & 7;
    int xcd = blockIdx.x & 7, slot = blockIdx.x >> 3;
    int newid = (xcd < r8 ? xcd * (q + 1) : r8 * (q + 1) + (xcd - r8) * q) + slot;
    const int row0 = (newid >> 2) * 128;   // col-fast: 4 col-blocks adjacent
    const int col0 = (newid & 3) * 128;

    f32x4 acc[4][4] = {};

    for (int k0 = 0; k0 < K; k0 += 32) {
#pragma unroll
        for (int h = 0; h < 2; ++h) {
            int ss = tid + h * 256;          // 0..511
            int r = ss >> 2;                 // 0..127
            int c = (ss & 3) ^ (r & 3);      // inverse-permuted source seg
            int ra = row0 + r; if (ra >= n) ra = n - 1;
            load_lds16(X + (size_t)ra * K + k0 + c * 8, &As[ss * 8]);
            load_lds16(Wt + (size_t)(col0 + r) * K + k0 + c * 8, &Bs[ss * 8]);
        }
        __syncthreads();

        bf16x8 af[4], bfr[4];
#pragma unroll
        for (int m = 0; m < 4; ++m) {
            int r = wr * 64 + m * 16 + (lane & 15);
            int seg = r * 4 + ((lane >> 4) ^ (r & 3));
            af[m] = *(const bf16x8*)&As[seg * 8];
        }
#pragma unroll
        for (int nn = 0; nn < 4; ++nn) {
            int r = wc * 64 + nn * 16 + (lane & 15);
            int seg = r * 4 + ((lane >> 4) ^ (r & 3));
            bfr[nn] = *(const bf16x8*)&Bs[seg * 8];
        }
#pragma unroll
        for (int m = 0; m < 4; ++m)
#pragma unroll
            for (int nn = 0; nn < 4; ++nn)
                acc[m][nn] = __builtin_amdgcn_mfma_f32_16x16x32_bf16(
                    af[m], bfr[nn], acc[m][nn], 0, 0, 0);
        __syncthreads();
    }

    const float ap = PRELU ? *prelu_a : 0.f;
#pragma unroll
    for (int m = 0; m < 4; ++m) {
        int gr_base = row0 + wr * 64 + m * 16 + (lane >> 4) * 4;
#pragma unroll
        for (int nn = 0; nn < 4; ++nn) {
            int gc = col0 + wc * 64 + nn * 16 + (lane & 15);
            float bv = bias[gc];
#pragma unroll
            for (int j = 0; j < 4; ++j) {
                int gr = gr_base + j;
                if (gr < n) {
                    float v = acc[m][nn][j] + bv;
                    if (PRELU) v = (v >= 0.f) ? v : ap * v;
                    if (OUT_BF16) ((bf16*)outv)[(size_t)gr * HID + gc] = (bf16)v;
                    else         ((float*)outv)[(size_t)gr * HID + gc] = v;
                }
            }
        }
    }
}

extern "C" void kernel_launch(void* const* d_in, const int* in_sizes, int n_in,
                              void* d_out, int out_size, void* d_ws, size_t ws_size,
                              hipStream_t stream) {
    const float* x  = (const float*)d_in[0];
    const void*  ei = d_in[1];
    const float* ew = (const float*)d_in[2];
    const float* W1 = (const float*)d_in[3];
    const float* b1 = (const float*)d_in[4];
    const float* W2 = (const float*)d_in[5];
    const float* b2 = (const float*)d_in[6];
    const float* pa = (const float*)d_in[7];

    char* base = (char*)d_ws;
    bf16*  aggb     = (bf16*)base;                          // 51.2 MB
    bf16*  xb       = (bf16*)(base + (size_t)N_NODES * HID * 2);   // 25.6 MB
    bf16*  W1b      = xb + (size_t)N_NODES * IN_CH;
    bf16*  W2b      = W1b + HID * IN_CH;
    float* deg      = (float*)(W2b + HID * HID);
    float* dis      = deg + N_NODES;
    int*   flag     = (int*)(dis + N_NODES);
    int*   counts   = flag + 1;
    int*   cursor   = counts + N_NODES;
    int*   row_ptr  = cursor + N_NODES;                     // N_NODES+1
    int*   srcs     = row_ptr + N_NODES + 1;                // N_EDGES
    float* coefs    = (float*)(srcs + N_EDGES);             // N_EDGES
    int*   partials = (int*)(coefs + N_EDGES);              // SCAN_NBLK

    bf16* p_bf = (bf16*)d_out;   // layer-1 bf16 output lives in d_out, consumed before GEMM2 writes f32

    const int NB = SCAN_NBLK;
    const int EB = (N_EDGES + 255) / 256;
    const int GEMM_NWG = (HID / 128) * ((N_NODES + 127) / 128);   // 4 * 391 = 1564

    // ----- CSR build (once, reused by both layers) -----
    init_arrays<<<NB, 256, 0, stream>>>(deg, counts, cursor, flag);
    detect_idx64_par<<<512, 256, 0, stream>>>((const unsigned int*)ei, flag);
    deg_hist<<<EB, 256, 0, stream>>>(ei, ew, deg, counts, flag);
    scan_partial<<<NB, 256, 0, stream>>>(counts, deg, dis, row_ptr, partials);
    scan_partials<<<1, 256, 0, stream>>>(partials, row_ptr);
    scan_add<<<NB, 256, 0, stream>>>(row_ptr, partials);
    fill_csr<<<EB, 256, 0, stream>>>(ei, ew, dis, row_ptr, cursor, srcs, coefs, flag);

    // ----- dtype conversions (weights scalar; x vectorized) -----
    f2b2_kernel<<<(HID * IN_CH + HID * HID + 255) / 256, 256, 0, stream>>>(
        W1, W1b, HID * IN_CH, W2, W2b, HID * HID);
    f2bx_kernel<<<(N_NODES * IN_CH / 8 + 255) / 256, 256, 0, stream>>>(x, xb);

    // ----- layer 1: gather bf16 x -> MFMA GEMM + bias + PReLU -> bf16 p (in d_out) -----
    gather_agg_c256<<<(N_NODES + 3) / 4, 256, 0, stream>>>(xb, dis, row_ptr, srcs, coefs, aggb);
    gemm_mfma<IN_CH, true, true><<<GEMM_NWG, 256, 0, stream>>>(
        aggb, W1b, b1, pa, p_bf, N_NODES);

    // ----- layer 2: gather bf16 p -> MFMA GEMM + bias -> f32 d_out -----
    gather_agg_c512<<<(N_NODES + 3) / 4, 256, 0, stream>>>(p_bf, dis, row_ptr, srcs, coefs, aggb);
    gemm_mfma<HID, false, false><<<GEMM_NWG, 256, 0, stream>>>(
        aggb, W2b, b2, pa, (float*)d_out, N_NODES);
}